// Round 1
// baseline (2088.631 us; speedup 1.0000x reference)
//
#include <hip/hip_runtime.h>
#include <cmath>

typedef unsigned short bf16_t;                                  // raw bf16 bits
typedef _Float16 f16_t;                                         // IEEE fp16
typedef __attribute__((ext_vector_type(8))) short short8;       // MFMA A/B frag
typedef __attribute__((ext_vector_type(4))) float f32x4;        // MFMA C/D frag
typedef _Float16 h2v __attribute__((ext_vector_type(2)));       // packed f16 pair
typedef _Float16 h8 __attribute__((ext_vector_type(8)));        // 16B f16 vector

#define NI_N 32768
#define NV_N 131072
#define E_VV 1048576
#define E_VI 524288
#define E_IV 524288
#define NT_N (NV_N+NV_N+NI_N)          // 294912 concatenated nodes (vv|iv|vi)
#define ET_N (E_VV+E_IV+E_VI)          // 2097152 concatenated edges
#define SC_WIN 4                        // scatter windows

__device__ __forceinline__ float bf2f(bf16_t u){ return __builtin_bit_cast(float,((unsigned)u)<<16); }
__device__ __forceinline__ bf16_t f2bf(float f){
  unsigned u=__builtin_bit_cast(unsigned,f);
  return (bf16_t)((u+0x7fffu+((u>>16)&1u))>>16);
}
__device__ __forceinline__ float gelu_f(float x){ return 0.5f*x*(1.0f+erff(x*0.7071067811865476f)); }

// split f32 into hi/lo bf16
__device__ __forceinline__ void splitf(float v, short& hi, short& lo){
  bf16_t h=f2bf(v);
  hi=(short)h;
  lo=(short)f2bf(v-bf2f(h));
}
__device__ __forceinline__ float ldval(const float* p){ return *p; }
__device__ __forceinline__ float ldval(const f16_t* p){ return (float)*p; }
__device__ __forceinline__ void stval(float* p,float v){ *p=v; }
__device__ __forceinline__ void stval(f16_t* p,float v){ *p=(f16_t)v; }
__device__ __forceinline__ h2v shxor(h2v a,int m){
  return __builtin_bit_cast(h2v,__shfl_xor(__builtin_bit_cast(int,a),m));
}

// ---------------- fused CSR build over 3 concatenated edge types ----------------
__global__ __launch_bounds__(256) void k_hist3(const int* __restrict__ dvv,const int* __restrict__ div_,
    const int* __restrict__ dvi,int* __restrict__ cnt){
  int i=blockIdx.x*256+threadIdx.x;
  if(i<E_VV) atomicAdd(&cnt[dvv[i]],1);
  else if(i<E_VV+E_IV) atomicAdd(&cnt[NV_N+div_[i-E_VV]],1);
  else atomicAdd(&cnt[2*NV_N+dvi[i-E_VV-E_IV]],1);
}
__global__ __launch_bounds__(512) void k_scan1(const int* __restrict__ cnt,int N,int* __restrict__ rp,int* __restrict__ bsum){
  __shared__ int sh[512];
  int i=blockIdx.x*512+threadIdx.x;
  int v=(i<N)?cnt[i]:0;
  sh[threadIdx.x]=v; __syncthreads();
  for(int off=1;off<512;off<<=1){
    int t=(threadIdx.x>=(unsigned)off)?sh[threadIdx.x-off]:0; __syncthreads();
    sh[threadIdx.x]+=t; __syncthreads();
  }
  if(i<N) rp[i]=sh[threadIdx.x]-v;
  if(threadIdx.x==511) bsum[blockIdx.x]=sh[511];
}
__global__ __launch_bounds__(1024) void k_scan2(const int* __restrict__ bsum,int* __restrict__ boff,int nb){
  __shared__ int sh[1024];
  int t=threadIdx.x;
  int v=(t<nb)?bsum[t]:0;
  sh[t]=v; __syncthreads();
  for(int off=1;off<1024;off<<=1){
    int x=(t>=(unsigned)off)?sh[t-off]:0; __syncthreads();
    sh[t]+=x; __syncthreads();
  }
  if(t<nb) boff[t]=sh[t]-v;
  if(t==1023) boff[nb]=sh[1023];
}
__global__ __launch_bounds__(512) void k_scan3(int* __restrict__ rp,const int* __restrict__ boff,int* __restrict__ cur,int N,int nb){
  int i=blockIdx.x*512+threadIdx.x;
  if(i<N){ int v=rp[i]+boff[i>>9]; rp[i]=v; cur[i]=v; }
  if(i==0) rp[N]=boff[nb];
}
__global__ __launch_bounds__(256) void k_scatter3w(const int* __restrict__ svv,const int* __restrict__ dvv,
    const int* __restrict__ siv,const int* __restrict__ div_,
    const int* __restrict__ svi,const int* __restrict__ dvi,
    int* __restrict__ cur,int* __restrict__ esrc,int dlo,int dhi){
  int i=blockIdx.x*256+threadIdx.x;
  int d,s;
  if(i<E_VV){ d=dvv[i]; if(d<dlo||d>=dhi) return; s=svv[i]; }
  else if(i<E_VV+E_IV){ int j=i-E_VV; d=NV_N+div_[j]; if(d<dlo||d>=dhi) return; s=siv[j]; }
  else { int j=i-E_VV-E_IV; d=2*NV_N+dvi[j]; if(d<dlo||d>=dhi) return; s=svi[j]; }
  int p=atomicAdd(&cur[d],1); esrc[p]=s;
}

// initial cast: f32 inputs -> f16 x buffers
__global__ __launch_bounds__(256) void k_castx(const float* __restrict__ xi_in,const float* __restrict__ xv_in,
    f16_t* __restrict__ xi,f16_t* __restrict__ xv){
  int i=blockIdx.x*256+threadIdx.x;
  if(i<NI_N*64) xi[i]=(f16_t)xi_in[i];
  else { int j=i-NI_N*64; xv[j]=(f16_t)xv_in[j]; }
}

// ---------------- weight folding for ALL 6 layers in one launch ----------------
struct FoldArgs{
  const float *Wk_i,*Wq_i,*Wv_i,*bk_i,*bq_i,*bv_i;
  const float *Wk_v,*Wq_v,*Wv_v,*bk_v,*bq_v,*bv_v;
  const float *arel_vv,*mrel_vv,*prel_vv,*arel_vi,*mrel_vi,*prel_vi,*arel_iv,*mrel_iv,*prel_iv;
  const float *Wa_i,*Wa_v;
  short *fwh_var,*fwl_var,*fwh_ins,*fwl_ins,*wah_i,*wal_i,*wah_v,*wal_v;
  float *fwb_var,*fwb_ins;
};
__global__ __launch_bounds__(256) void k_fold6(FoldArgs fa){
  int gid=blockIdx.x*256+threadIdx.x;
  if(gid>=6*640*64) return;
  int l=gid/(640*64);
  int rem=gid-l*640*64;
  int r=rem>>6, c=rem&63;
  if(r>=512){
    int ro=r&63;
    const float* W=(r<576)?fa.Wa_i:fa.Wa_v;
    short *sh=((r<576)?fa.wah_i:fa.wah_v)+l*4096, *sl=((r<576)?fa.wal_i:fa.wal_v)+l*4096;
    short h,lo; splitf(W[l*4096+ro*64+c],h,lo);
    sh[ro*64+c]=h; sl[ro*64+c]=lo;
    return;
  }
  const float *W,*B,*rel=nullptr,*prl=nullptr;
  short *sh,*sl; float *fwb; int orow;
  if(r<320){
    sh=fa.fwh_var+l*320*64; sl=fa.fwl_var+l*320*64; fwb=fa.fwb_var+l*320; orow=r;
    if(r<64){ W=fa.Wq_v; B=fa.bq_v; }
    else if(r<128){ W=fa.Wk_v; B=fa.bk_v; rel=fa.arel_vv; prl=fa.prel_vv; }
    else if(r<192){ W=fa.Wv_v; B=fa.bv_v; rel=fa.mrel_vv; }
    else if(r<256){ W=fa.Wk_v; B=fa.bk_v; rel=fa.arel_vi; prl=fa.prel_vi; }
    else         { W=fa.Wv_v; B=fa.bv_v; rel=fa.mrel_vi; }
  }else{
    int rr=r-320; sh=fa.fwh_ins+l*192*64; sl=fa.fwl_ins+l*192*64; fwb=fa.fwb_ins+l*192; orow=rr;
    if(rr<64){ W=fa.Wq_i; B=fa.bq_i; }
    else if(rr<128){ W=fa.Wk_i; B=fa.bk_i; rel=fa.arel_iv; prl=fa.prel_iv; }
    else           { W=fa.Wv_i; B=fa.bv_i; rel=fa.mrel_iv; }
  }
  int ro=orow&63;
  float val,bval;
  if(!rel){
    val=W[l*4096+ro*64+c]; bval=B[l*64+ro];
  }else{
    int h=ro>>3, e=ro&7;
    float s=prl?prl[l*8+h]*0.3535533905932738f:1.0f;
    float acc=0.f,bacc=0.f;
    #pragma unroll
    for(int d=0;d<8;d++){
      float rv=rel[l*512+h*64+d*8+e];
      acc += W[l*4096+(h*8+d)*64+c]*rv;
      bacc+= B[l*64+h*8+d]*rv;
    }
    val=acc*s; bval=bacc*s;
  }
  short h2q,lo2; splitf(val,h2q,lo2);
  sh[orow*64+c]=h2q; sl[orow*64+c]=lo2;
  if(c==0) fwb[orow]=bval;
}

__global__ __launch_bounds__(256) void k_split2(const float* __restrict__ W,int n,short* __restrict__ hi,short* __restrict__ lo){
  int i=blockIdx.x*256+threadIdx.x;
  if(i<n){ short h,l2; splitf(W[i],h,l2); hi[i]=h; lo[i]=l2; }
}

// ---------------- shared split-bf16 GEMM body with LDS-repacked wide f16 stores ----------------
// rep: per-wave LDS tile [16][72] (f16), nullptr-free for f16 out; float out stores directly.
template<typename AT, typename OT>
__device__ __forceinline__ void gemm_body(const AT* __restrict__ A,int row0,
    const short* __restrict__ Bh,const short* __restrict__ Bl,
    const float* __restrict__ bias,float bias_scale,
    OT* __restrict__ out,int octot,int ocol0,int npanels,int m,int quad,int lane,
    f16_t (*rep)[72])
{
  const AT* ap=A+(size_t)(row0+m)*64+quad*8;
  short8 ahi[2], alo[2];
  #pragma unroll
  for(int kf=0;kf<2;kf++){
    short8 th,tl;
    #pragma unroll
    for(int j=0;j<8;j++){ short h,l2; splitf(ldval(&ap[kf*32+j]),h,l2); th[j]=h; tl[j]=l2; }
    ahi[kf]=th; alo[kf]=tl;
  }
  for(int pan=0;pan<npanels;pan++){
    int colbase=pan*64;
    short8 bhi[4][2], blo[4][2];
    #pragma unroll
    for(int ot=0;ot<4;ot++){
      size_t o=(size_t)(colbase+ot*16+m)*64+quad*8;
      #pragma unroll
      for(int kf=0;kf<2;kf++){
        bhi[ot][kf]=*(const short8*)(Bh+o+kf*32);
        blo[ot][kf]=*(const short8*)(Bl+o+kf*32);
      }
    }
    f32x4 acc[4];
    #pragma unroll
    for(int ot=0;ot<4;ot++){
      float bv=bias[colbase+ot*16+m]*bias_scale;
      acc[ot][0]=bv; acc[ot][1]=bv; acc[ot][2]=bv; acc[ot][3]=bv;
    }
    #pragma unroll
    for(int ot=0;ot<4;ot++){
      #pragma unroll
      for(int kf=0;kf<2;kf++){
        acc[ot]=__builtin_amdgcn_mfma_f32_16x16x32_bf16(alo[kf],bhi[ot][kf],acc[ot],0,0,0);
        acc[ot]=__builtin_amdgcn_mfma_f32_16x16x32_bf16(ahi[kf],blo[ot][kf],acc[ot],0,0,0);
        acc[ot]=__builtin_amdgcn_mfma_f32_16x16x32_bf16(ahi[kf],bhi[ot][kf],acc[ot],0,0,0);
      }
    }
    if constexpr(sizeof(OT)==2){
      // repack via LDS, store wide
      #pragma unroll
      for(int ot=0;ot<4;ot++)
        #pragma unroll
        for(int r=0;r<4;r++)
          rep[quad*4+r][ot*16+m]=(f16_t)acc[ot][r];
      #pragma unroll
      for(int it=0;it<2;it++){
        int rr=it*8+(lane>>3), seg=lane&7;
        h8 vals=*(const h8*)&rep[rr][seg*8];
        *(h8*)(out+(size_t)(row0+rr)*octot+ocol0+colbase+seg*8)=vals;
      }
    }else{
      #pragma unroll
      for(int ot=0;ot<4;ot++){
        int col=ocol0+colbase+ot*16+m;
        #pragma unroll
        for(int r=0;r<4;r++){
          int row=row0+quad*4+r;
          stval(&out[(size_t)row*octot+col],acc[ot][r]);
        }
      }
    }
  }
}

template<typename AT, typename OT>
__global__ __launch_bounds__(256) void k_gemm64p(const AT* __restrict__ A,int N,
    const short* __restrict__ Bh,const short* __restrict__ Bl,
    const float* __restrict__ bias,float bias_scale,
    OT* __restrict__ out,int octot,int ocol0,int npanels)
{
  __shared__ f16_t rep[4][16][72];
  const int wave=threadIdx.x>>6, lane=threadIdx.x&63;
  const int m=lane&15, quad=lane>>4;
  const int row0=blockIdx.x*64+wave*16;
  if(row0>=N) return;
  gemm_body<AT,OT>(A,row0,Bh,Bl,bias,bias_scale,out,octot,ocol0,npanels,m,quad,lane,rep[wave]);
}

// fused feature GEMM: blocks [0,nbv) var rows (5 panels, stride 320), rest ins rows (3 panels, 192)
__global__ __launch_bounds__(256) void k_gemm_feat(const f16_t* __restrict__ Av,const f16_t* __restrict__ Ai,
    const short* __restrict__ Bvh,const short* __restrict__ Bvl,const float* __restrict__ biasv,
    const short* __restrict__ Bih,const short* __restrict__ Bil,const float* __restrict__ biasi,
    f16_t* __restrict__ outv,f16_t* __restrict__ outi,int nbv)
{
  __shared__ f16_t rep[4][16][72];
  const int wave=threadIdx.x>>6, lane=threadIdx.x&63;
  const int m=lane&15, quad=lane>>4;
  if((int)blockIdx.x<nbv){
    int row0=blockIdx.x*64+wave*16;
    gemm_body<f16_t,f16_t>(Av,row0,Bvh,Bvl,biasv,1.0f,outv,320,0,5,m,quad,lane,rep[wave]);
  }else{
    int row0=(blockIdx.x-nbv)*64+wave*16;
    gemm_body<f16_t,f16_t>(Ai,row0,Bih,Bil,biasi,1.0f,outi,192,0,3,m,quad,lane,rep[wave]);
  }
}

// ---------------- fused per-layer update (instr blocks then var blocks), x/agg f16, LDS-repacked I/O ----------------
__global__ __launch_bounds__(256) void k_update2(const f16_t* __restrict__ agg_i,const f16_t* __restrict__ agg_v,
    const short* __restrict__ wah_i,const short* __restrict__ wal_i,
    const short* __restrict__ wah_v,const short* __restrict__ wal_v,
    const float* __restrict__ ba_i,const float* __restrict__ ba_v,
    const float* __restrict__ skip_i,const float* __restrict__ skip_v,
    f16_t* __restrict__ x_i,f16_t* __restrict__ x_v,
    f16_t* __restrict__ outs,int nbi)
{
  __shared__ f16_t rep[4][16][72];
  const int wave=threadIdx.x>>6, lane=threadIdx.x&63;
  const int m=lane&15, quad=lane>>4;
  const bool isI=(int)blockIdx.x<nbi;
  const int row0=(isI?blockIdx.x:(blockIdx.x-nbi))*64+wave*16;
  const f16_t* agg=isI?agg_i:agg_v;
  const short* Wah=isI?wah_i:wah_v;
  const short* Wal=isI?wal_i:wal_v;
  const float* ba=isI?ba_i:ba_v;
  const float* skip=isI?skip_i:skip_v;
  f16_t* x=isI?x_i:x_v;
  f16_t* oo=isI?outs:nullptr;
  f16_t (*R)[72]=rep[wave];
  short8 bhi[4][2], blo[4][2];
  #pragma unroll
  for(int ot=0;ot<4;ot++){
    size_t o=(size_t)(ot*16+m)*64+quad*8;
    #pragma unroll
    for(int kf=0;kf<2;kf++){
      bhi[ot][kf]=*(const short8*)(Wah+o+kf*32);
      blo[ot][kf]=*(const short8*)(Wal+o+kf*32);
    }
  }
  const f16_t* ap=agg+(size_t)(row0+m)*64+quad*8;
  short8 ahi[2], alo[2];
  #pragma unroll
  for(int kf=0;kf<2;kf++){
    short8 th,tl;
    #pragma unroll
    for(int j=0;j<8;j++){ short h,l2; splitf(gelu_f((float)ap[kf*32+j]),h,l2); th[j]=h; tl[j]=l2; }
    ahi[kf]=th; alo[kf]=tl;
  }
  // stage x rows into LDS (wide loads)
  int rr0=lane>>3, seg=lane&7;
  h8 x0=*(const h8*)(x+(size_t)(row0+rr0)*64+seg*8);
  h8 x1=*(const h8*)(x+(size_t)(row0+8+rr0)*64+seg*8);
  *(h8*)&R[rr0][seg*8]=x0;
  *(h8*)&R[8+rr0][seg*8]=x1;
  f32x4 acc[4];
  #pragma unroll
  for(int ot=0;ot<4;ot++){
    float bv=ba[ot*16+m];
    acc[ot][0]=bv; acc[ot][1]=bv; acc[ot][2]=bv; acc[ot][3]=bv;
  }
  #pragma unroll
  for(int ot=0;ot<4;ot++){
    #pragma unroll
    for(int kf=0;kf<2;kf++){
      acc[ot]=__builtin_amdgcn_mfma_f32_16x16x32_bf16(alo[kf],bhi[ot][kf],acc[ot],0,0,0);
      acc[ot]=__builtin_amdgcn_mfma_f32_16x16x32_bf16(ahi[kf],blo[ot][kf],acc[ot],0,0,0);
      acc[ot]=__builtin_amdgcn_mfma_f32_16x16x32_bf16(ahi[kf],bhi[ot][kf],acc[ot],0,0,0);
    }
  }
  float s=1.0f/(1.0f+__expf(-skip[0]));
  // blend against LDS-staged x, write result back into the SAME cells (each cell owned by one lane)
  #pragma unroll
  for(int ot=0;ot<4;ot++){
    int col=ot*16+m;
    #pragma unroll
    for(int r=0;r<4;r++){
      int row=quad*4+r;
      float xn=s*acc[ot][r]+(1.0f-s)*(float)R[row][col];
      R[row][col]=(f16_t)xn;
    }
  }
  // wide write-back
  h8 o0=*(const h8*)&R[rr0][seg*8];
  h8 o1=*(const h8*)&R[8+rr0][seg*8];
  *(h8*)(x+(size_t)(row0+rr0)*64+seg*8)=o0;
  *(h8*)(x+(size_t)(row0+8+rr0)*64+seg*8)=o1;
  if(oo){
    *(h8*)(oo+(size_t)(row0+rr0)*64+seg*8)=o0;
    *(h8*)(oo+(size_t)(row0+8+rr0)*64+seg*8)=o1;
  }
}

// ---------------- edge attention: lane = feature dim, 4-edge unroll, packed-f16 dots ----------------
__device__ __forceinline__ float edge_aggD(const int* __restrict__ rp,const int* __restrict__ es,
    const f16_t* __restrict__ sf,int stride,int koff,int voff,int n,int lane,f16_t qh)
{
  int b=__builtin_amdgcn_readfirstlane(rp[n]);
  int e=__builtin_amdgcn_readfirstlane(rp[n+1]);
  float m=-INFINITY, ls=0.f, acc=0.f;
  h2v q2={qh,qh};
  int i=b;
  for(; i+3<e; i+=4){
    int s0=__builtin_amdgcn_readfirstlane(es[i]);
    int s1=__builtin_amdgcn_readfirstlane(es[i+1]);
    int s2=__builtin_amdgcn_readfirstlane(es[i+2]);
    int s3=__builtin_amdgcn_readfirstlane(es[i+3]);
    const f16_t* r0=sf+(size_t)s0*stride;
    const f16_t* r1=sf+(size_t)s1*stride;
    const f16_t* r2=sf+(size_t)s2*stride;
    const f16_t* r3=sf+(size_t)s3*stride;
    f16_t k0=r0[koff+lane], k1=r1[koff+lane], k2=r2[koff+lane], k3=r3[koff+lane];
    float v0=(float)r0[voff+lane], v1=(float)r1[voff+lane];
    float v2=(float)r2[voff+lane], v3=(float)r3[voff+lane];
    h2v pa={k0,k1}; pa=q2*pa;
    h2v pb={k2,k3}; pb=q2*pb;
    pa=pa+shxor(pa,1); pb=pb+shxor(pb,1);
    pa=pa+shxor(pa,2); pb=pb+shxor(pb,2);
    pa=pa+shxor(pa,4); pb=pb+shxor(pb,4);
    float p0=(float)pa[0], p1=(float)pa[1], p2=(float)pb[0], p3=(float)pb[1];
    float mn=fmaxf(fmaxf(m,fmaxf(p0,p1)),fmaxf(p2,p3));
    float sc=__expf(m-mn);            // first iter: exp(-inf)=0
    float w0=__expf(p0-mn), w1=__expf(p1-mn), w2=__expf(p2-mn), w3=__expf(p3-mn);
    ls=ls*sc+((w0+w1)+(w2+w3));
    acc=acc*sc+((w0*v0+w1*v1)+(w2*v2+w3*v3));
    m=mn;
  }
  float qf=(float)qh;
  for(; i<e; i++){
    int s0=__builtin_amdgcn_readfirstlane(es[i]);
    const f16_t* r0=sf+(size_t)s0*stride;
    float k0=(float)r0[koff+lane], v0=(float)r0[voff+lane];
    float p0=qf*k0;
    p0+=__shfl_xor(p0,1); p0+=__shfl_xor(p0,2); p0+=__shfl_xor(p0,4);
    float mn=fmaxf(m,p0);
    float sc=__expf(m-mn), w0=__expf(p0-mn);
    ls=ls*sc+w0;
    acc=acc*sc+w0*v0;
    m=mn;
  }
  return acc/(ls+1e-16f);   // degree 0 -> 0, matches PyG semantics
}

// fused edge kernel: blocks [0,nbv) var destinations (vv+iv), rest instr destinations (vi)
__global__ __launch_bounds__(256) void k_edge_all(const int* __restrict__ rp_all,const int* __restrict__ es,
    const f16_t* __restrict__ var_feat,const f16_t* __restrict__ ins_feat,
    f16_t* __restrict__ agg_v,f16_t* __restrict__ agg_i,int nbv)
{
  int wave=threadIdx.x>>6, lane=threadIdx.x&63;
  if((int)blockIdx.x<nbv){
    int n=blockIdx.x*4+wave;
    f16_t qh=var_feat[(size_t)n*320+lane];
    float r1=edge_aggD(rp_all,es,var_feat,320,64,128,n,lane,qh);
    float r2=edge_aggD(rp_all+NV_N,es,ins_feat,192,64,128,n,lane,qh);
    agg_v[(size_t)n*64+lane]=(f16_t)(r1+r2);
  }else{
    int n=(blockIdx.x-nbv)*4+wave;
    f16_t qh=ins_feat[(size_t)n*192+lane];
    float r=edge_aggD(rp_all+2*NV_N,es,var_feat,320,192,256,n,lane,qh);
    agg_i[(size_t)n*64+lane]=(f16_t)r;
  }
}

// ---------------- jumping-knowledge 5x5 attention, one wave per node
__global__ __launch_bounds__(256) void k_jk(const f16_t* __restrict__ qkv,float* __restrict__ osum,int n_nodes){
  int wave=threadIdx.x>>6, lane=threadIdx.x&63;
  int n=blockIdx.x*4+wave;
  if(n>=n_nodes) return;
  float q[5],k[5],v[5];
  #pragma unroll
  for(int s=0;s<5;s++){
    const f16_t* p=qkv+((size_t)s*n_nodes+n)*192;
    q[s]=(float)p[lane]; k[s]=(float)p[64+lane]; v[s]=(float)p[128+lane];
  }
  float sc[5][5];
  #pragma unroll
  for(int s=0;s<5;s++)
    #pragma unroll
    for(int t=0;t<5;t++){
      float x=q[s]*k[t];
      x+=__shfl_xor(x,1); x+=__shfl_xor(x,2); x+=__shfl_xor(x,4);
      sc[s][t]=x*0.3535533905932738f;
    }
  float os=0.f;
  #pragma unroll
  for(int s=0;s<5;s++){
    float m=sc[s][0];
    #pragma unroll
    for(int t=1;t<5;t++) m=fmaxf(m,sc[s][t]);
    float den=0.f, acc=0.f;
    #pragma unroll
    for(int t=0;t<5;t++){ float e=__expf(sc[s][t]-m); den+=e; acc+=e*v[t]; }
    os+=acc/den;
  }
  osum[(size_t)n*64+lane]=os;
}

// ---------------- MLP head ----------------
struct MlpArgs{ const float *w0,*b0,*w1,*b1,*w2,*b2,*w3,*b3,*w4,*b4,*w5,*b5; };
__global__ __launch_bounds__(256) void k_mlp(const float* __restrict__ in,MlpArgs ma,float* __restrict__ out,int N){
  __shared__ float sw0[2048],sb0[32],sw1[512],sb1[16],sw2[128],sb2[8],sw3[32],sb3[4],sw4[8],sb4[2],sw5[2],sb5[1];
  for(int i=threadIdx.x;i<2048;i+=256) sw0[i]=ma.w0[i];
  for(int i=threadIdx.x;i<512;i+=256)  sw1[i]=ma.w1[i];
  if(threadIdx.x<128) sw2[threadIdx.x]=ma.w2[threadIdx.x];
  if(threadIdx.x<32){ sb0[threadIdx.x]=ma.b0[threadIdx.x]; sw3[threadIdx.x]=ma.w3[threadIdx.x]; }
  if(threadIdx.x<16) sb1[threadIdx.x]=ma.b1[threadIdx.x];
  if(threadIdx.x<8){ sb2[threadIdx.x]=ma.b2[threadIdx.x]; sw4[threadIdx.x]=ma.w4[threadIdx.x]; }
  if(threadIdx.x<4) sb3[threadIdx.x]=ma.b3[threadIdx.x];
  if(threadIdx.x<2){ sb4[threadIdx.x]=ma.b4[threadIdx.x]; sw5[threadIdx.x]=ma.w5[threadIdx.x]; }
  if(threadIdx.x==0) sb5[0]=ma.b5[0];
  __syncthreads();
  int n=blockIdx.x*256+threadIdx.x;
  if(n>=N) return;
  float a[64];
  const f32x4* p4=(const f32x4*)(in+(size_t)n*64);
  #pragma unroll
  for(int j=0;j<16;j++){ f32x4 t=p4[j]; a[4*j]=t[0]; a[4*j+1]=t[1]; a[4*j+2]=t[2]; a[4*j+3]=t[3]; }
  float h1[32];
  #pragma unroll
  for(int o=0;o<32;o++){ float s=sb0[o];
    #pragma unroll
    for(int c=0;c<64;c++) s+=a[c]*sw0[o*64+c];
    h1[o]=gelu_f(s); }
  float h2q[16];
  #pragma unroll
  for(int o=0;o<16;o++){ float s=sb1[o];
    #pragma unroll
    for(int c=0;c<32;c++) s+=h1[c]*sw1[o*32+c];
    h2q[o]=gelu_f(s); }
  float h3[8];
  #pragma unroll
  for(int o=0;o<8;o++){ float s=sb2[o];
    #pragma unroll
    for(int c=0;c<16;c++) s+=h2q[c]*sw2[o*16+c];
    h3[o]=gelu_f(s); }
  float h4[4];
  #pragma unroll
  for(int o=0;o<4;o++){ float s=sb3[o];
    #pragma unroll
    for(int c=0;c<8;c++) s+=h3[c]*sw3[o*8+c];
    h4[o]=gelu_f(s); }
  float h5[2];
  #pragma unroll
  for(int o=0;o<2;o++){ float s=sb4[o];
    #pragma unroll
    for(int c=0;c<4;c++) s+=h4[c]*sw4[o*4+c];
    h5[o]=gelu_f(s); }
  float r=sb5[0]+h5[0]*sw5[0]+h5[1]*sw5[1];
  out[n]=r;
}

// ================= host launcher =================
extern "C" void kernel_launch(void* const* d_in,const int* in_sizes,int n_in,
                              void* d_out,int out_size,void* d_ws,size_t ws_size,
                              hipStream_t stream){
  (void)in_sizes;(void)n_in;(void)out_size;(void)ws_size;
  const float* x_instr=(const float*)d_in[0];
  const float* x_var  =(const float*)d_in[1];
  const float* ba_i=(const float*)d_in[9];
  const float* skip_i=(const float*)d_in[10];
  const float* ba_v=(const float*)d_in[18];
  const float* skip_v=(const float*)d_in[19];
  const float* Wqkv=(const float*)d_in[29];
  const float* bqkv=(const float*)d_in[30];
  const float* Wo=(const float*)d_in[31];
  const float* bo=(const float*)d_in[32];
  const int* src_vv=(const int*)d_in[45];
  const int* dst_vv=(const int*)d_in[46];
  const int* src_vi=(const int*)d_in[47];
  const int* dst_vi=(const int*)d_in[48];
  const int* src_iv=(const int*)d_in[49];
  const int* dst_iv=(const int*)d_in[50];

  char* w=(char*)d_ws;
  auto alloc=[&](size_t b)->char*{ char* p=w; w+=(b+255)&~(size_t)255; return p; };
  // ---- fused CSR arrays (~12 MB) ----
  int* rp_all=(int*)alloc((size_t)(NT_N+1)*4);
  int* cnt_all=(int*)alloc((size_t)NT_N*4);
  int* cur_all=(int*)alloc((size_t)NT_N*4);
  int* bsum =(int*)alloc(640*4);
  int* boff =(int*)alloc(640*4);
  int* esrc_all=(int*)alloc((size_t)ET_N*4);
  // ---- folded + pre-split weights for all 6 layers (~2.5 MB) ----
  short* fwh_var=(short*)alloc((size_t)6*320*64*2);
  short* fwl_var=(short*)alloc((size_t)6*320*64*2);
  float* fwb_var=(float*)alloc((size_t)6*320*4);
  short* fwh_ins=(short*)alloc((size_t)6*192*64*2);
  short* fwl_ins=(short*)alloc((size_t)6*192*64*2);
  float* fwb_ins=(float*)alloc((size_t)6*192*4);
  short* wah_i=(short*)alloc((size_t)6*64*64*2);
  short* wal_i=(short*)alloc((size_t)6*64*64*2);
  short* wah_v=(short*)alloc((size_t)6*64*64*2);
  short* wal_v=(short*)alloc((size_t)6*64*64*2);
  short* qkvh=(short*)alloc(192*64*2);
  short* qkvl=(short*)alloc(192*64*2);
  short* woh=(short*)alloc(64*64*2);
  short* wol=(short*)alloc(64*64*2);
  // ---- persistent across phases: outs (f16, 21 MB) ----
  f16_t* outs=(f16_t*)alloc((size_t)5*NI_N*64*2);
  // ---- arena (140 MB), phase-overlaid ----
  char* arena=alloc((size_t)146800640);
  f16_t*  xv      =(f16_t*)(arena);                                // 16,777,216 B
  f16_t*  xi      =(f16_t*)(arena+16777216);                       //  4,194,304 B
  f16_t*  var_feat=(f16_t*)(arena+20971520);                       // 83,886,080 B (stride 320: q|k_vv|v_vv|k_vi|v_vi)
  f16_t*  ins_feat=(f16_t*)(arena+104857600);                      // 12,582,912 B (stride 192: q|k|v)
  f16_t*  agg_v   =(f16_t*)(arena+117440512);                      // 16,777,216 B
  f16_t*  agg_i   =(f16_t*)(arena+134217728);                      //  4,194,304 B
  // JK phase overlays (xv/xi/var_feat dead by then):
  f16_t*  qkv    =(f16_t*)(arena);                                 // 62,914,560 B
  float*  osum   =(float*)(arena+67108864);                        //  8,388,608 B (inside dead var_feat)
  float*  out_jk =(float*)(arena+75497472);                        //  8,388,608 B (inside dead var_feat)

  // fused CSR build
  hipMemsetAsync(cnt_all,0,(size_t)NT_N*4,stream);
  k_hist3<<<ET_N/256,256,0,stream>>>(dst_vv,dst_iv,dst_vi,cnt_all);
  int nb=NT_N/512;   // 576
  k_scan1<<<nb,512,0,stream>>>(cnt_all,NT_N,rp_all,bsum);
  k_scan2<<<1,1024,0,stream>>>(bsum,boff,nb);
  k_scan3<<<nb,512,0,stream>>>(rp_all,boff,cur_all,NT_N,nb);
  for(int wdx=0;wdx<SC_WIN;wdx++){
    int dlo=wdx*(NT_N/SC_WIN), dhi=(wdx+1)*(NT_N/SC_WIN);
    k_scatter3w<<<ET_N/256,256,0,stream>>>(src_vv,dst_vv,src_iv,dst_iv,src_vi,dst_vi,cur_all,esrc_all,dlo,dhi);
  }

  k_castx<<<(NI_N*64+NV_N*64)/256,256,0,stream>>>(x_instr,x_var,xi,xv);

  // one-time splits for JK weights
  k_split2<<<(192*64+255)/256,256,0,stream>>>(Wqkv,192*64,qkvh,qkvl);
  k_split2<<<(64*64+255)/256,256,0,stream>>>(Wo,64*64,woh,wol);

  FoldArgs fa;
  fa.Wk_i=(const float*)d_in[2]; fa.Wq_i=(const float*)d_in[3]; fa.Wv_i=(const float*)d_in[4];
  fa.bk_i=(const float*)d_in[6]; fa.bq_i=(const float*)d_in[7]; fa.bv_i=(const float*)d_in[8];
  fa.Wk_v=(const float*)d_in[11]; fa.Wq_v=(const float*)d_in[12]; fa.Wv_v=(const float*)d_in[13];
  fa.bk_v=(const float*)d_in[15]; fa.bq_v=(const float*)d_in[16]; fa.bv_v=(const float*)d_in[17];
  fa.arel_vv=(const float*)d_in[20]; fa.mrel_vv=(const float*)d_in[21]; fa.prel_vv=(const float*)d_in[22];
  fa.arel_vi=(const float*)d_in[23]; fa.mrel_vi=(const float*)d_in[24]; fa.prel_vi=(const float*)d_in[25];
  fa.arel_iv=(const float*)d_in[26]; fa.mrel_iv=(const float*)d_in[27]; fa.prel_iv=(const float*)d_in[28];
  fa.Wa_i=(const float*)d_in[5]; fa.Wa_v=(const float*)d_in[14];
  fa.fwh_var=fwh_var; fa.fwl_var=fwl_var; fa.fwh_ins=fwh_ins; fa.fwl_ins=fwl_ins;
  fa.wah_i=wah_i; fa.wal_i=wal_i; fa.wah_v=wah_v; fa.wal_v=wal_v;
  fa.fwb_var=fwb_var; fa.fwb_ins=fwb_ins;
  k_fold6<<<(6*640*64)/256,256,0,stream>>>(fa);

  for(int l=0;l<6;l++){
    k_gemm_feat<<<NV_N/64+NI_N/64,256,0,stream>>>(xv,xi,
        fwh_var+(size_t)l*320*64,fwl_var+(size_t)l*320*64,fwb_var+l*320,
        fwh_ins+(size_t)l*192*64,fwl_ins+(size_t)l*192*64,fwb_ins+l*192,
        var_feat,ins_feat,NV_N/64);
    k_edge_all<<<NV_N/4+NI_N/4,256,0,stream>>>(rp_all,esrc_all,var_feat,ins_feat,agg_v,agg_i,NV_N/4);
    k_update2<<<NI_N/64+NV_N/64,256,0,stream>>>(agg_i,agg_v,
        wah_i+(size_t)l*4096,wal_i+(size_t)l*4096,wah_v+(size_t)l*4096,wal_v+(size_t)l*4096,
        ba_i+l*64,ba_v+l*64,skip_i+l,skip_v+l,xi,xv,
        (l>0)?(outs+(size_t)(l-1)*NI_N*64):nullptr,NI_N/64);
  }

  // jumping knowledge + head
  k_gemm64p<f16_t,f16_t><<<5*NI_N/64,256,0,stream>>>(outs,5*NI_N,qkvh,qkvl,bqkv,1.0f,qkv,192,0,3);
  k_jk<<<NI_N/4,256,0,stream>>>(qkv,osum,NI_N);
  k_gemm64p<float,float><<<NI_N/64,256,0,stream>>>(osum,NI_N,woh,wol,bo,5.0f,out_jk,64,0,1);
  MlpArgs ma;
  ma.w0=(const float*)d_in[33]; ma.b0=(const float*)d_in[34];
  ma.w1=(const float*)d_in[35]; ma.b1=(const float*)d_in[36];
  ma.w2=(const float*)d_in[37]; ma.b2=(const float*)d_in[38];
  ma.w3=(const float*)d_in[39]; ma.b3=(const float*)d_in[40];
  ma.w4=(const float*)d_in[41]; ma.b4=(const float*)d_in[42];
  ma.w5=(const float*)d_in[43]; ma.b5=(const float*)d_in[44];
  k_mlp<<<NI_N/256,256,0,stream>>>(out_jk,ma,(float*)d_out,NI_N);
}

// Round 2
// 1984.262 us; speedup vs baseline: 1.0526x; 1.0526x over previous
//
#include <hip/hip_runtime.h>
#include <cmath>

typedef _Float16 f16_t;                                         // IEEE fp16
typedef __attribute__((ext_vector_type(8))) short short8;       // MFMA A/B frag (bit container)
typedef __attribute__((ext_vector_type(8))) _Float16 half8;     // MFMA f16 frag
typedef __attribute__((ext_vector_type(4))) float f32x4;        // MFMA C/D frag
typedef _Float16 h2v __attribute__((ext_vector_type(2)));       // packed f16 pair
typedef _Float16 h8 __attribute__((ext_vector_type(8)));        // 16B f16 vector

#define NI_N 32768
#define NV_N 131072
#define E_VV 1048576
#define E_VI 524288
#define E_IV 524288
#define NT_N (NV_N+NV_N+NI_N)          // 294912 concatenated nodes (vv|iv|vi)
#define ET_N (E_VV+E_IV+E_VI)          // 2097152 concatenated edges
#define SC_WIN 4                        // scatter windows
#define LOG2E 1.4426950408889634f

__device__ __forceinline__ float gelu_f(float x){ return 0.5f*x*(1.0f+erff(x*0.7071067811865476f)); }

// split f32 into hi/lo f16 (hi+lo carries ~22 bits of mantissa)
__device__ __forceinline__ void splitf16(float v, short& hi, short& lo){
  f16_t h=(f16_t)v;
  hi=__builtin_bit_cast(short,h);
  f16_t l=(f16_t)(v-(float)h);
  lo=__builtin_bit_cast(short,l);
}
__device__ __forceinline__ f32x4 mfma16(short8 a, short8 b, f32x4 c){
  return __builtin_amdgcn_mfma_f32_16x16x32_f16(__builtin_bit_cast(half8,a),__builtin_bit_cast(half8,b),c,0,0,0);
}
__device__ __forceinline__ float fexp2(float x){
#if __has_builtin(__builtin_amdgcn_exp2f)
  return __builtin_amdgcn_exp2f(x);
#else
  return exp2f(x);
#endif
}
__device__ __forceinline__ float ldval(const float* p){ return *p; }
__device__ __forceinline__ float ldval(const f16_t* p){ return (float)*p; }
__device__ __forceinline__ void stval(float* p,float v){ *p=v; }
__device__ __forceinline__ void stval(f16_t* p,float v){ *p=(f16_t)v; }
__device__ __forceinline__ h2v shxor(h2v a,int m){
  return __builtin_bit_cast(h2v,__shfl_xor(__builtin_bit_cast(int,a),m));
}

// ---------------- fused CSR build over 3 concatenated edge types ----------------
__global__ __launch_bounds__(256) void k_hist3(const int* __restrict__ dvv,const int* __restrict__ div_,
    const int* __restrict__ dvi,int* __restrict__ cnt){
  int i=blockIdx.x*256+threadIdx.x;
  if(i<E_VV) atomicAdd(&cnt[dvv[i]],1);
  else if(i<E_VV+E_IV) atomicAdd(&cnt[NV_N+div_[i-E_VV]],1);
  else atomicAdd(&cnt[2*NV_N+dvi[i-E_VV-E_IV]],1);
}
__global__ __launch_bounds__(512) void k_scan1(const int* __restrict__ cnt,int N,int* __restrict__ rp,int* __restrict__ bsum){
  __shared__ int sh[512];
  int i=blockIdx.x*512+threadIdx.x;
  int v=(i<N)?cnt[i]:0;
  sh[threadIdx.x]=v; __syncthreads();
  for(int off=1;off<512;off<<=1){
    int t=(threadIdx.x>=(unsigned)off)?sh[threadIdx.x-off]:0; __syncthreads();
    sh[threadIdx.x]+=t; __syncthreads();
  }
  if(i<N) rp[i]=sh[threadIdx.x]-v;
  if(threadIdx.x==511) bsum[blockIdx.x]=sh[511];
}
__global__ __launch_bounds__(1024) void k_scan2(const int* __restrict__ bsum,int* __restrict__ boff,int nb){
  __shared__ int sh[1024];
  int t=threadIdx.x;
  int v=(t<nb)?bsum[t]:0;
  sh[t]=v; __syncthreads();
  for(int off=1;off<1024;off<<=1){
    int x=(t>=(unsigned)off)?sh[t-off]:0; __syncthreads();
    sh[t]+=x; __syncthreads();
  }
  if(t<nb) boff[t]=sh[t]-v;
  if(t==1023) boff[nb]=sh[1023];
}
__global__ __launch_bounds__(512) void k_scan3(int* __restrict__ rp,const int* __restrict__ boff,int* __restrict__ cur,int N,int nb){
  int i=blockIdx.x*512+threadIdx.x;
  if(i<N){ int v=rp[i]+boff[i>>9]; rp[i]=v; cur[i]=v; }
  if(i==0) rp[N]=boff[nb];
}
__global__ __launch_bounds__(256) void k_scatter3w(const int* __restrict__ svv,const int* __restrict__ dvv,
    const int* __restrict__ siv,const int* __restrict__ div_,
    const int* __restrict__ svi,const int* __restrict__ dvi,
    int* __restrict__ cur,int* __restrict__ esrc,int dlo,int dhi){
  int i=blockIdx.x*256+threadIdx.x;
  int d,s;
  if(i<E_VV){ d=dvv[i]; if(d<dlo||d>=dhi) return; s=svv[i]; }
  else if(i<E_VV+E_IV){ int j=i-E_VV; d=NV_N+div_[j]; if(d<dlo||d>=dhi) return; s=siv[j]; }
  else { int j=i-E_VV-E_IV; d=2*NV_N+dvi[j]; if(d<dlo||d>=dhi) return; s=svi[j]; }
  int p=atomicAdd(&cur[d],1); esrc[p]=s;
}

// initial cast: f32 inputs -> f16 x buffers
__global__ __launch_bounds__(256) void k_castx(const float* __restrict__ xi_in,const float* __restrict__ xv_in,
    f16_t* __restrict__ xi,f16_t* __restrict__ xv){
  int i=blockIdx.x*256+threadIdx.x;
  if(i<NI_N*64) xi[i]=(f16_t)xi_in[i];
  else { int j=i-NI_N*64; xv[j]=(f16_t)xv_in[j]; }
}

// ---------------- weight folding for ALL 6 layers in one launch ----------------
// NEW layout: k/v output columns interleaved (k_d -> base+2d, v_d -> base+2d+1) so the
// edge kernel fetches {k,v} with ONE dword load. q columns scaled by LOG2E for exp2 softmax.
struct FoldArgs{
  const float *Wk_i,*Wq_i,*Wv_i,*bk_i,*bq_i,*bv_i;
  const float *Wk_v,*Wq_v,*Wv_v,*bk_v,*bq_v,*bv_v;
  const float *arel_vv,*mrel_vv,*prel_vv,*arel_vi,*mrel_vi,*prel_vi,*arel_iv,*mrel_iv,*prel_iv;
  const float *Wa_i,*Wa_v;
  short *fwh_var,*fwl_var,*fwh_ins,*fwl_ins,*wah_i,*wal_i,*wah_v,*wal_v;
  float *fwb_var,*fwb_ins;
};
__global__ __launch_bounds__(256) void k_fold6(FoldArgs fa){
  int gid=blockIdx.x*256+threadIdx.x;
  if(gid>=6*640*64) return;
  int l=gid/(640*64);
  int rem=gid-l*640*64;
  int r=rem>>6, c=rem&63;
  if(r>=512){
    int ro=r&63;
    const float* W=(r<576)?fa.Wa_i:fa.Wa_v;
    short *sh=((r<576)?fa.wah_i:fa.wah_v)+l*4096, *sl=((r<576)?fa.wal_i:fa.wal_v)+l*4096;
    short h,lo; splitf16(W[l*4096+ro*64+c],h,lo);
    sh[ro*64+c]=h; sl[ro*64+c]=lo;
    return;
  }
  const float *W,*B,*rel=nullptr,*prl=nullptr;
  short *sh,*sl; float *fwb; int orow,d; bool isq=false;
  if(r<320){
    sh=fa.fwh_var+l*320*64; sl=fa.fwl_var+l*320*64; fwb=fa.fwb_var+l*320;
    d=r&63;
    if(r<64){ W=fa.Wq_v; B=fa.bq_v; orow=d; isq=true; }
    else if(r<128){ W=fa.Wk_v; B=fa.bk_v; rel=fa.arel_vv; prl=fa.prel_vv; orow=64+2*d; }
    else if(r<192){ W=fa.Wv_v; B=fa.bv_v; rel=fa.mrel_vv; orow=64+2*d+1; }
    else if(r<256){ W=fa.Wk_v; B=fa.bk_v; rel=fa.arel_vi; prl=fa.prel_vi; orow=192+2*d; }
    else         { W=fa.Wv_v; B=fa.bv_v; rel=fa.mrel_vi; orow=192+2*d+1; }
  }else{
    int rr=r-320; sh=fa.fwh_ins+l*192*64; sl=fa.fwl_ins+l*192*64; fwb=fa.fwb_ins+l*192;
    d=rr&63;
    if(rr<64){ W=fa.Wq_i; B=fa.bq_i; orow=d; isq=true; }
    else if(rr<128){ W=fa.Wk_i; B=fa.bk_i; rel=fa.arel_iv; prl=fa.prel_iv; orow=64+2*d; }
    else           { W=fa.Wv_i; B=fa.bv_i; rel=fa.mrel_iv; orow=64+2*d+1; }
  }
  float val,bval;
  if(!rel){
    val=W[l*4096+d*64+c]; bval=B[l*64+d];
  }else{
    int h=d>>3, e=d&7;
    float s=prl?prl[l*8+h]*0.3535533905932738f:1.0f;
    float acc=0.f,bacc=0.f;
    #pragma unroll
    for(int dd=0;dd<8;dd++){
      float rv=rel[l*512+h*64+dd*8+e];
      acc += W[l*4096+(h*8+dd)*64+c]*rv;
      bacc+= B[l*64+h*8+dd]*rv;
    }
    val=acc*s; bval=bacc*s;
  }
  if(isq){ val*=LOG2E; bval*=LOG2E; }
  short h2q,lo2; splitf16(val,h2q,lo2);
  sh[orow*64+c]=h2q; sl[orow*64+c]=lo2;
  if(c==0) fwb[orow]=bval;
}

__global__ __launch_bounds__(256) void k_split2(const float* __restrict__ W,int n,short* __restrict__ hi,short* __restrict__ lo){
  int i=blockIdx.x*256+threadIdx.x;
  if(i<n){ short h,l2; splitf16(W[i],h,l2); hi[i]=h; lo[i]=l2; }
}

// ---------------- shared f16-MFMA GEMM body with LDS-repacked wide f16 stores ----------------
// f16 A: used directly (exact), 2 MFMA per (ot,kf). float A: split to f16 hi/lo, 3 MFMA.
// B always f16 hi/lo split (~22-bit effective precision).
template<typename AT, typename OT>
__device__ __forceinline__ void gemm_body(const AT* __restrict__ A,int row0,
    const short* __restrict__ Bh,const short* __restrict__ Bl,
    const float* __restrict__ bias,float bias_scale,
    OT* __restrict__ out,int octot,int ocol0,int npanels,int m,int quad,int lane,
    f16_t (*rep)[72])
{
  const AT* ap=A+(size_t)(row0+m)*64+quad*8;
  constexpr bool AF16 = (sizeof(AT)==2);
  short8 ahi[2], alo[2];
  if constexpr(AF16){
    #pragma unroll
    for(int kf=0;kf<2;kf++) ahi[kf]=*(const short8*)(const void*)(ap+kf*32);
  }else{
    #pragma unroll
    for(int kf=0;kf<2;kf++){
      short8 th,tl;
      #pragma unroll
      for(int j=0;j<8;j++){ short h,l2; splitf16(ldval(&ap[kf*32+j]),h,l2); th[j]=h; tl[j]=l2; }
      ahi[kf]=th; alo[kf]=tl;
    }
  }
  for(int pan=0;pan<npanels;pan++){
    int colbase=pan*64;
    short8 bhi[4][2], blo[4][2];
    #pragma unroll
    for(int ot=0;ot<4;ot++){
      size_t o=(size_t)(colbase+ot*16+m)*64+quad*8;
      #pragma unroll
      for(int kf=0;kf<2;kf++){
        bhi[ot][kf]=*(const short8*)(Bh+o+kf*32);
        blo[ot][kf]=*(const short8*)(Bl+o+kf*32);
      }
    }
    f32x4 acc[4];
    #pragma unroll
    for(int ot=0;ot<4;ot++){
      float bv=bias[colbase+ot*16+m]*bias_scale;
      acc[ot][0]=bv; acc[ot][1]=bv; acc[ot][2]=bv; acc[ot][3]=bv;
    }
    #pragma unroll
    for(int ot=0;ot<4;ot++){
      #pragma unroll
      for(int kf=0;kf<2;kf++){
        if constexpr(!AF16) acc[ot]=mfma16(alo[kf],bhi[ot][kf],acc[ot]);
        acc[ot]=mfma16(ahi[kf],blo[ot][kf],acc[ot]);
        acc[ot]=mfma16(ahi[kf],bhi[ot][kf],acc[ot]);
      }
    }
    if constexpr(sizeof(OT)==2){
      // repack via LDS, store wide
      #pragma unroll
      for(int ot=0;ot<4;ot++)
        #pragma unroll
        for(int r=0;r<4;r++)
          rep[quad*4+r][ot*16+m]=(f16_t)acc[ot][r];
      #pragma unroll
      for(int it=0;it<2;it++){
        int rr=it*8+(lane>>3), seg=lane&7;
        h8 vals=*(const h8*)&rep[rr][seg*8];
        *(h8*)(out+(size_t)(row0+rr)*octot+ocol0+colbase+seg*8)=vals;
      }
    }else{
      #pragma unroll
      for(int ot=0;ot<4;ot++){
        int col=ocol0+colbase+ot*16+m;
        #pragma unroll
        for(int r=0;r<4;r++){
          int row=row0+quad*4+r;
          stval(&out[(size_t)row*octot+col],acc[ot][r]);
        }
      }
    }
  }
}

template<typename AT, typename OT>
__global__ __launch_bounds__(256) void k_gemm64p(const AT* __restrict__ A,int N,
    const short* __restrict__ Bh,const short* __restrict__ Bl,
    const float* __restrict__ bias,float bias_scale,
    OT* __restrict__ out,int octot,int ocol0,int npanels)
{
  __shared__ f16_t rep[4][16][72];
  const int wave=threadIdx.x>>6, lane=threadIdx.x&63;
  const int m=lane&15, quad=lane>>4;
  const int row0=blockIdx.x*64+wave*16;
  if(row0>=N) return;
  gemm_body<AT,OT>(A,row0,Bh,Bl,bias,bias_scale,out,octot,ocol0,npanels,m,quad,lane,rep[wave]);
}

// fused feature GEMM: blocks [0,nbv) var rows (5 panels, stride 320), rest ins rows (3 panels, 192)
__global__ __launch_bounds__(256) void k_gemm_feat(const f16_t* __restrict__ Av,const f16_t* __restrict__ Ai,
    const short* __restrict__ Bvh,const short* __restrict__ Bvl,const float* __restrict__ biasv,
    const short* __restrict__ Bih,const short* __restrict__ Bil,const float* __restrict__ biasi,
    f16_t* __restrict__ outv,f16_t* __restrict__ outi,int nbv)
{
  __shared__ f16_t rep[4][16][72];
  const int wave=threadIdx.x>>6, lane=threadIdx.x&63;
  const int m=lane&15, quad=lane>>4;
  if((int)blockIdx.x<nbv){
    int row0=blockIdx.x*64+wave*16;
    gemm_body<f16_t,f16_t>(Av,row0,Bvh,Bvl,biasv,1.0f,outv,320,0,5,m,quad,lane,rep[wave]);
  }else{
    int row0=(blockIdx.x-nbv)*64+wave*16;
    gemm_body<f16_t,f16_t>(Ai,row0,Bih,Bil,biasi,1.0f,outi,192,0,3,m,quad,lane,rep[wave]);
  }
}

// ---------------- fused per-layer update (instr blocks then var blocks), x/agg f16, LDS-repacked I/O ----------------
__global__ __launch_bounds__(256) void k_update2(const f16_t* __restrict__ agg_i,const f16_t* __restrict__ agg_v,
    const short* __restrict__ wah_i,const short* __restrict__ wal_i,
    const short* __restrict__ wah_v,const short* __restrict__ wal_v,
    const float* __restrict__ ba_i,const float* __restrict__ ba_v,
    const float* __restrict__ skip_i,const float* __restrict__ skip_v,
    f16_t* __restrict__ x_i,f16_t* __restrict__ x_v,
    f16_t* __restrict__ outs,int nbi)
{
  __shared__ f16_t rep[4][16][72];
  const int wave=threadIdx.x>>6, lane=threadIdx.x&63;
  const int m=lane&15, quad=lane>>4;
  const bool isI=(int)blockIdx.x<nbi;
  const int row0=(isI?blockIdx.x:(blockIdx.x-nbi))*64+wave*16;
  const f16_t* agg=isI?agg_i:agg_v;
  const short* Wah=isI?wah_i:wah_v;
  const short* Wal=isI?wal_i:wal_v;
  const float* ba=isI?ba_i:ba_v;
  const float* skip=isI?skip_i:skip_v;
  f16_t* x=isI?x_i:x_v;
  f16_t* oo=isI?outs:nullptr;
  f16_t (*R)[72]=rep[wave];
  short8 bhi[4][2], blo[4][2];
  #pragma unroll
  for(int ot=0;ot<4;ot++){
    size_t o=(size_t)(ot*16+m)*64+quad*8;
    #pragma unroll
    for(int kf=0;kf<2;kf++){
      bhi[ot][kf]=*(const short8*)(Wah+o+kf*32);
      blo[ot][kf]=*(const short8*)(Wal+o+kf*32);
    }
  }
  const f16_t* ap=agg+(size_t)(row0+m)*64+quad*8;
  short8 ahi[2], alo[2];
  #pragma unroll
  for(int kf=0;kf<2;kf++){
    short8 th,tl;
    #pragma unroll
    for(int j=0;j<8;j++){ short h,l2; splitf16(gelu_f((float)ap[kf*32+j]),h,l2); th[j]=h; tl[j]=l2; }
    ahi[kf]=th; alo[kf]=tl;
  }
  // stage x rows into LDS (wide loads)
  int rr0=lane>>3, seg=lane&7;
  h8 x0=*(const h8*)(x+(size_t)(row0+rr0)*64+seg*8);
  h8 x1=*(const h8*)(x+(size_t)(row0+8+rr0)*64+seg*8);
  *(h8*)&R[rr0][seg*8]=x0;
  *(h8*)&R[8+rr0][seg*8]=x1;
  f32x4 acc[4];
  #pragma unroll
  for(int ot=0;ot<4;ot++){
    float bv=ba[ot*16+m];
    acc[ot][0]=bv; acc[ot][1]=bv; acc[ot][2]=bv; acc[ot][3]=bv;
  }
  #pragma unroll
  for(int ot=0;ot<4;ot++){
    #pragma unroll
    for(int kf=0;kf<2;kf++){
      acc[ot]=mfma16(alo[kf],bhi[ot][kf],acc[ot]);
      acc[ot]=mfma16(ahi[kf],blo[ot][kf],acc[ot]);
      acc[ot]=mfma16(ahi[kf],bhi[ot][kf],acc[ot]);
    }
  }
  float s=1.0f/(1.0f+__expf(-skip[0]));
  // blend against LDS-staged x, write result back into the SAME cells (each cell owned by one lane)
  #pragma unroll
  for(int ot=0;ot<4;ot++){
    int col=ot*16+m;
    #pragma unroll
    for(int r=0;r<4;r++){
      int row=quad*4+r;
      float xn=s*acc[ot][r]+(1.0f-s)*(float)R[row][col];
      R[row][col]=(f16_t)xn;
    }
  }
  // wide write-back
  h8 o0=*(const h8*)&R[rr0][seg*8];
  h8 o1=*(const h8*)&R[8+rr0][seg*8];
  *(h8*)(x+(size_t)(row0+rr0)*64+seg*8)=o0;
  *(h8*)(x+(size_t)(row0+8+rr0)*64+seg*8)=o1;
  if(oo){
    *(h8*)(oo+(size_t)(row0+rr0)*64+seg*8)=o0;
    *(h8*)(oo+(size_t)(row0+8+rr0)*64+seg*8)=o1;
  }
}

// ---------------- edge attention: lane = feature dim, 4-edge unroll, interleaved {k,v} dword gathers ----------------
// kv block layout: k_d at koff+2d, v_d at koff+2d+1. logits pre-scaled by LOG2E -> exp2.
__device__ __forceinline__ float edge_aggI(const int* __restrict__ rp,const int* __restrict__ es,
    const f16_t* __restrict__ sf,int stride,int koff,int n,int lane,f16_t qh)
{
  int b=__builtin_amdgcn_readfirstlane(rp[n]);
  int e=__builtin_amdgcn_readfirstlane(rp[n+1]);
  float m=-INFINITY, ls=0.f, acc=0.f;
  h2v q2={qh,qh};
  const int lo2=koff+2*lane;
  int i=b;
  for(; i+3<e; i+=4){
    int s0=__builtin_amdgcn_readfirstlane(es[i]);
    int s1=__builtin_amdgcn_readfirstlane(es[i+1]);
    int s2=__builtin_amdgcn_readfirstlane(es[i+2]);
    int s3=__builtin_amdgcn_readfirstlane(es[i+3]);
    h2v kv0=*(const h2v*)(sf+(size_t)s0*stride+lo2);
    h2v kv1=*(const h2v*)(sf+(size_t)s1*stride+lo2);
    h2v kv2=*(const h2v*)(sf+(size_t)s2*stride+lo2);
    h2v kv3=*(const h2v*)(sf+(size_t)s3*stride+lo2);
    h2v pa={kv0[0],kv1[0]}; pa=q2*pa;
    h2v pb={kv2[0],kv3[0]}; pb=q2*pb;
    pa=pa+shxor(pa,1); pb=pb+shxor(pb,1);
    pa=pa+shxor(pa,2); pb=pb+shxor(pb,2);
    pa=pa+shxor(pa,4); pb=pb+shxor(pb,4);
    float p0=(float)pa[0], p1=(float)pa[1], p2=(float)pb[0], p3=(float)pb[1];
    float v0=(float)kv0[1], v1=(float)kv1[1];
    float v2=(float)kv2[1], v3=(float)kv3[1];
    float mn=fmaxf(fmaxf(m,fmaxf(p0,p1)),fmaxf(p2,p3));
    float sc=fexp2(m-mn);            // first iter: exp2(-inf)=0
    float w0=fexp2(p0-mn), w1=fexp2(p1-mn), w2=fexp2(p2-mn), w3=fexp2(p3-mn);
    ls=ls*sc+((w0+w1)+(w2+w3));
    acc=acc*sc+((w0*v0+w1*v1)+(w2*v2+w3*v3));
    m=mn;
  }
  float qf=(float)qh;
  for(; i<e; i++){
    int s0=__builtin_amdgcn_readfirstlane(es[i]);
    h2v kv=*(const h2v*)(sf+(size_t)s0*stride+lo2);
    float p0=qf*(float)kv[0];
    p0+=__shfl_xor(p0,1); p0+=__shfl_xor(p0,2); p0+=__shfl_xor(p0,4);
    float mn=fmaxf(m,p0);
    float sc=fexp2(m-mn), w0=fexp2(p0-mn);
    ls=ls*sc+w0;
    acc=acc*sc+w0*(float)kv[1];
    m=mn;
  }
  return acc/(ls+1e-16f);   // degree 0 -> 0, matches PyG semantics
}

// fused edge kernel: blocks [0,nbv) var destinations (vv+iv), rest instr destinations (vi)
__global__ __launch_bounds__(256) void k_edge_all(const int* __restrict__ rp_all,const int* __restrict__ es,
    const f16_t* __restrict__ var_feat,const f16_t* __restrict__ ins_feat,
    f16_t* __restrict__ agg_v,f16_t* __restrict__ agg_i,int nbv)
{
  int wave=threadIdx.x>>6, lane=threadIdx.x&63;
  if((int)blockIdx.x<nbv){
    int n=blockIdx.x*4+wave;
    f16_t qh=var_feat[(size_t)n*320+lane];
    float r1=edge_aggI(rp_all,es,var_feat,320,64,n,lane,qh);
    float r2=edge_aggI(rp_all+NV_N,es,ins_feat,192,64,n,lane,qh);
    agg_v[(size_t)n*64+lane]=(f16_t)(r1+r2);
  }else{
    int n=(blockIdx.x-nbv)*4+wave;
    f16_t qh=ins_feat[(size_t)n*192+lane];
    float r=edge_aggI(rp_all+2*NV_N,es,var_feat,320,192,n,lane,qh);
    agg_i[(size_t)n*64+lane]=(f16_t)r;
  }
}

// ---------------- jumping-knowledge 5x5 attention, one wave per node
__global__ __launch_bounds__(256) void k_jk(const f16_t* __restrict__ qkv,float* __restrict__ osum,int n_nodes){
  int wave=threadIdx.x>>6, lane=threadIdx.x&63;
  int n=blockIdx.x*4+wave;
  if(n>=n_nodes) return;
  float q[5],k[5],v[5];
  #pragma unroll
  for(int s=0;s<5;s++){
    const f16_t* p=qkv+((size_t)s*n_nodes+n)*192;
    q[s]=(float)p[lane]; k[s]=(float)p[64+lane]; v[s]=(float)p[128+lane];
  }
  float sc[5][5];
  #pragma unroll
  for(int s=0;s<5;s++)
    #pragma unroll
    for(int t=0;t<5;t++){
      float x=q[s]*k[t];
      x+=__shfl_xor(x,1); x+=__shfl_xor(x,2); x+=__shfl_xor(x,4);
      sc[s][t]=x*0.3535533905932738f;
    }
  float os=0.f;
  #pragma unroll
  for(int s=0;s<5;s++){
    float m=sc[s][0];
    #pragma unroll
    for(int t=1;t<5;t++) m=fmaxf(m,sc[s][t]);
    float den=0.f, acc=0.f;
    #pragma unroll
    for(int t=0;t<5;t++){ float e=__expf(sc[s][t]-m); den+=e; acc+=e*v[t]; }
    os+=acc/den;
  }
  osum[(size_t)n*64+lane]=os;
}

// ---------------- MLP head ----------------
struct MlpArgs{ const float *w0,*b0,*w1,*b1,*w2,*b2,*w3,*b3,*w4,*b4,*w5,*b5; };
__global__ __launch_bounds__(256) void k_mlp(const float* __restrict__ in,MlpArgs ma,float* __restrict__ out,int N){
  __shared__ float sw0[2048],sb0[32],sw1[512],sb1[16],sw2[128],sb2[8],sw3[32],sb3[4],sw4[8],sb4[2],sw5[2],sb5[1];
  for(int i=threadIdx.x;i<2048;i+=256) sw0[i]=ma.w0[i];
  for(int i=threadIdx.x;i<512;i+=256)  sw1[i]=ma.w1[i];
  if(threadIdx.x<128) sw2[threadIdx.x]=ma.w2[threadIdx.x];
  if(threadIdx.x<32){ sb0[threadIdx.x]=ma.b0[threadIdx.x]; sw3[threadIdx.x]=ma.w3[threadIdx.x]; }
  if(threadIdx.x<16) sb1[threadIdx.x]=ma.b1[threadIdx.x];
  if(threadIdx.x<8){ sb2[threadIdx.x]=ma.b2[threadIdx.x]; sw4[threadIdx.x]=ma.w4[threadIdx.x]; }
  if(threadIdx.x<4) sb3[threadIdx.x]=ma.b3[threadIdx.x];
  if(threadIdx.x<2){ sb4[threadIdx.x]=ma.b4[threadIdx.x]; sw5[threadIdx.x]=ma.w5[threadIdx.x]; }
  if(threadIdx.x==0) sb5[0]=ma.b5[0];
  __syncthreads();
  int n=blockIdx.x*256+threadIdx.x;
  if(n>=N) return;
  float a[64];
  const f32x4* p4=(const f32x4*)(in+(size_t)n*64);
  #pragma unroll
  for(int j=0;j<16;j++){ f32x4 t=p4[j]; a[4*j]=t[0]; a[4*j+1]=t[1]; a[4*j+2]=t[2]; a[4*j+3]=t[3]; }
  float h1[32];
  #pragma unroll
  for(int o=0;o<32;o++){ float s=sb0[o];
    #pragma unroll
    for(int c=0;c<64;c++) s+=a[c]*sw0[o*64+c];
    h1[o]=gelu_f(s); }
  float h2q[16];
  #pragma unroll
  for(int o=0;o<16;o++){ float s=sb1[o];
    #pragma unroll
    for(int c=0;c<32;c++) s+=h1[c]*sw1[o*32+c];
    h2q[o]=gelu_f(s); }
  float h3[8];
  #pragma unroll
  for(int o=0;o<8;o++){ float s=sb2[o];
    #pragma unroll
    for(int c=0;c<16;c++) s+=h2q[c]*sw2[o*16+c];
    h3[o]=gelu_f(s); }
  float h4[4];
  #pragma unroll
  for(int o=0;o<4;o++){ float s=sb3[o];
    #pragma unroll
    for(int c=0;c<8;c++) s+=h3[c]*sw3[o*8+c];
    h4[o]=gelu_f(s); }
  float h5[2];
  #pragma unroll
  for(int o=0;o<2;o++){ float s=sb4[o];
    #pragma unroll
    for(int c=0;c<4;c++) s+=h4[c]*sw4[o*4+c];
    h5[o]=gelu_f(s); }
  float r=sb5[0]+h5[0]*sw5[0]+h5[1]*sw5[1];
  out[n]=r;
}

// ================= host launcher =================
extern "C" void kernel_launch(void* const* d_in,const int* in_sizes,int n_in,
                              void* d_out,int out_size,void* d_ws,size_t ws_size,
                              hipStream_t stream){
  (void)in_sizes;(void)n_in;(void)out_size;(void)ws_size;
  const float* x_instr=(const float*)d_in[0];
  const float* x_var  =(const float*)d_in[1];
  const float* ba_i=(const float*)d_in[9];
  const float* skip_i=(const float*)d_in[10];
  const float* ba_v=(const float*)d_in[18];
  const float* skip_v=(const float*)d_in[19];
  const float* Wqkv=(const float*)d_in[29];
  const float* bqkv=(const float*)d_in[30];
  const float* Wo=(const float*)d_in[31];
  const float* bo=(const float*)d_in[32];
  const int* src_vv=(const int*)d_in[45];
  const int* dst_vv=(const int*)d_in[46];
  const int* src_vi=(const int*)d_in[47];
  const int* dst_vi=(const int*)d_in[48];
  const int* src_iv=(const int*)d_in[49];
  const int* dst_iv=(const int*)d_in[50];

  char* w=(char*)d_ws;
  auto alloc=[&](size_t b)->char*{ char* p=w; w+=(b+255)&~(size_t)255; return p; };
  // ---- fused CSR arrays (~12 MB) ----
  int* rp_all=(int*)alloc((size_t)(NT_N+1)*4);
  int* cnt_all=(int*)alloc((size_t)NT_N*4);
  int* cur_all=(int*)alloc((size_t)NT_N*4);
  int* bsum =(int*)alloc(640*4);
  int* boff =(int*)alloc(640*4);
  int* esrc_all=(int*)alloc((size_t)ET_N*4);
  // ---- folded + pre-split weights for all 6 layers (~2.5 MB) ----
  short* fwh_var=(short*)alloc((size_t)6*320*64*2);
  short* fwl_var=(short*)alloc((size_t)6*320*64*2);
  float* fwb_var=(float*)alloc((size_t)6*320*4);
  short* fwh_ins=(short*)alloc((size_t)6*192*64*2);
  short* fwl_ins=(short*)alloc((size_t)6*192*64*2);
  float* fwb_ins=(float*)alloc((size_t)6*192*4);
  short* wah_i=(short*)alloc((size_t)6*64*64*2);
  short* wal_i=(short*)alloc((size_t)6*64*64*2);
  short* wah_v=(short*)alloc((size_t)6*64*64*2);
  short* wal_v=(short*)alloc((size_t)6*64*64*2);
  short* qkvh=(short*)alloc(192*64*2);
  short* qkvl=(short*)alloc(192*64*2);
  short* woh=(short*)alloc(64*64*2);
  short* wol=(short*)alloc(64*64*2);
  // ---- persistent across phases: outs (f16, 21 MB) ----
  f16_t* outs=(f16_t*)alloc((size_t)5*NI_N*64*2);
  // ---- arena (140 MB), phase-overlaid ----
  char* arena=alloc((size_t)146800640);
  f16_t*  xv      =(f16_t*)(arena);                                // 16,777,216 B
  f16_t*  xi      =(f16_t*)(arena+16777216);                       //  4,194,304 B
  f16_t*  var_feat=(f16_t*)(arena+20971520);                       // 83,886,080 B (stride 320: q | kv_vv interleaved | kv_vi interleaved)
  f16_t*  ins_feat=(f16_t*)(arena+104857600);                      // 12,582,912 B (stride 192: q | kv interleaved)
  f16_t*  agg_v   =(f16_t*)(arena+117440512);                      // 16,777,216 B
  f16_t*  agg_i   =(f16_t*)(arena+134217728);                      //  4,194,304 B
  // JK phase overlays (xv/xi/var_feat dead by then):
  f16_t*  qkv    =(f16_t*)(arena);                                 // 62,914,560 B
  float*  osum   =(float*)(arena+67108864);                        //  8,388,608 B (inside dead var_feat)
  float*  out_jk =(float*)(arena+75497472);                        //  8,388,608 B (inside dead var_feat)

  // fused CSR build
  hipMemsetAsync(cnt_all,0,(size_t)NT_N*4,stream);
  k_hist3<<<ET_N/256,256,0,stream>>>(dst_vv,dst_iv,dst_vi,cnt_all);
  int nb=NT_N/512;   // 576
  k_scan1<<<nb,512,0,stream>>>(cnt_all,NT_N,rp_all,bsum);
  k_scan2<<<1,1024,0,stream>>>(bsum,boff,nb);
  k_scan3<<<nb,512,0,stream>>>(rp_all,boff,cur_all,NT_N,nb);
  for(int wdx=0;wdx<SC_WIN;wdx++){
    int dlo=wdx*(NT_N/SC_WIN), dhi=(wdx+1)*(NT_N/SC_WIN);
    k_scatter3w<<<ET_N/256,256,0,stream>>>(src_vv,dst_vv,src_iv,dst_iv,src_vi,dst_vi,cur_all,esrc_all,dlo,dhi);
  }

  k_castx<<<(NI_N*64+NV_N*64)/256,256,0,stream>>>(x_instr,x_var,xi,xv);

  // one-time splits for JK weights
  k_split2<<<(192*64+255)/256,256,0,stream>>>(Wqkv,192*64,qkvh,qkvl);
  k_split2<<<(64*64+255)/256,256,0,stream>>>(Wo,64*64,woh,wol);

  FoldArgs fa;
  fa.Wk_i=(const float*)d_in[2]; fa.Wq_i=(const float*)d_in[3]; fa.Wv_i=(const float*)d_in[4];
  fa.bk_i=(const float*)d_in[6]; fa.bq_i=(const float*)d_in[7]; fa.bv_i=(const float*)d_in[8];
  fa.Wk_v=(const float*)d_in[11]; fa.Wq_v=(const float*)d_in[12]; fa.Wv_v=(const float*)d_in[13];
  fa.bk_v=(const float*)d_in[15]; fa.bq_v=(const float*)d_in[16]; fa.bv_v=(const float*)d_in[17];
  fa.arel_vv=(const float*)d_in[20]; fa.mrel_vv=(const float*)d_in[21]; fa.prel_vv=(const float*)d_in[22];
  fa.arel_vi=(const float*)d_in[23]; fa.mrel_vi=(const float*)d_in[24]; fa.prel_vi=(const float*)d_in[25];
  fa.arel_iv=(const float*)d_in[26]; fa.mrel_iv=(const float*)d_in[27]; fa.prel_iv=(const float*)d_in[28];
  fa.Wa_i=(const float*)d_in[5]; fa.Wa_v=(const float*)d_in[14];
  fa.fwh_var=fwh_var; fa.fwl_var=fwl_var; fa.fwh_ins=fwh_ins; fa.fwl_ins=fwl_ins;
  fa.wah_i=wah_i; fa.wal_i=wal_i; fa.wah_v=wah_v; fa.wal_v=wal_v;
  fa.fwb_var=fwb_var; fa.fwb_ins=fwb_ins;
  k_fold6<<<(6*640*64)/256,256,0,stream>>>(fa);

  for(int l=0;l<6;l++){
    k_gemm_feat<<<NV_N/64+NI_N/64,256,0,stream>>>(xv,xi,
        fwh_var+(size_t)l*320*64,fwl_var+(size_t)l*320*64,fwb_var+l*320,
        fwh_ins+(size_t)l*192*64,fwl_ins+(size_t)l*192*64,fwb_ins+l*192,
        var_feat,ins_feat,NV_N/64);
    k_edge_all<<<NV_N/4+NI_N/4,256,0,stream>>>(rp_all,esrc_all,var_feat,ins_feat,agg_v,agg_i,NV_N/4);
    k_update2<<<NI_N/64+NV_N/64,256,0,stream>>>(agg_i,agg_v,
        wah_i+(size_t)l*4096,wal_i+(size_t)l*4096,wah_v+(size_t)l*4096,wal_v+(size_t)l*4096,
        ba_i+l*64,ba_v+l*64,skip_i+l,skip_v+l,xi,xv,
        (l>0)?(outs+(size_t)(l-1)*NI_N*64):nullptr,NI_N/64);
  }

  // jumping knowledge + head
  k_gemm64p<f16_t,f16_t><<<5*NI_N/64,256,0,stream>>>(outs,5*NI_N,qkvh,qkvl,bqkv,1.0f,qkv,192,0,3);
  k_jk<<<NI_N/4,256,0,stream>>>(qkv,osum,NI_N);
  k_gemm64p<float,float><<<NI_N/64,256,0,stream>>>(osum,NI_N,woh,wol,bo,5.0f,out_jk,64,0,1);
  MlpArgs ma;
  ma.w0=(const float*)d_in[33]; ma.b0=(const float*)d_in[34];
  ma.w1=(const float*)d_in[35]; ma.b1=(const float*)d_in[36];
  ma.w2=(const float*)d_in[37]; ma.b2=(const float*)d_in[38];
  ma.w3=(const float*)d_in[39]; ma.b3=(const float*)d_in[40];
  ma.w4=(const float*)d_in[41]; ma.b4=(const float*)d_in[42];
  ma.w5=(const float*)d_in[43]; ma.b5=(const float*)d_in[44];
  k_mlp<<<NI_N/256,256,0,stream>>>(out_jk,ma,(float*)d_out,NI_N);
}

// Round 3
// 1635.798 us; speedup vs baseline: 1.2768x; 1.2130x over previous
//
#include <hip/hip_runtime.h>
#include <cmath>

typedef _Float16 f16_t;                                         // IEEE fp16
typedef __attribute__((ext_vector_type(8))) short short8;       // MFMA A/B frag (bit container)
typedef __attribute__((ext_vector_type(8))) _Float16 half8;     // MFMA f16 frag
typedef __attribute__((ext_vector_type(4))) float f32x4;        // MFMA C/D frag
typedef _Float16 h2v __attribute__((ext_vector_type(2)));       // packed f16 pair
typedef _Float16 h8 __attribute__((ext_vector_type(8)));        // 16B f16 vector

#define NI_N 32768
#define NV_N 131072
#define E_VV 1048576
#define E_VI 524288
#define E_IV 524288
#define NT_N (NV_N+NV_N+NI_N)          // 294912 concatenated nodes (vv|iv|vi)
#define ET_N (E_VV+E_IV+E_VI)          // 2097152 concatenated edges
#define SC_WIN 4                        // scatter windows
#define LOG2E 1.4426950408889634f
#define CHV 192                         // row-chunks per var panel (colres)
#define CHI 64                          // row-chunks per ins panel
#define CHQ 256                         // row-chunks per qkv panel

__device__ __forceinline__ float gelu_f(float x){ return 0.5f*x*(1.0f+erff(x*0.7071067811865476f)); }

// split f32 into hi/lo f16 (hi+lo carries ~22 bits of mantissa)
__device__ __forceinline__ void splitf16(float v, short& hi, short& lo){
  f16_t h=(f16_t)v;
  hi=__builtin_bit_cast(short,h);
  f16_t l=(f16_t)(v-(float)h);
  lo=__builtin_bit_cast(short,l);
}
__device__ __forceinline__ f32x4 mfma16(short8 a, short8 b, f32x4 c){
  return __builtin_amdgcn_mfma_f32_16x16x32_f16(__builtin_bit_cast(half8,a),__builtin_bit_cast(half8,b),c,0,0,0);
}
__device__ __forceinline__ float fexp2(float x){
#if __has_builtin(__builtin_amdgcn_exp2f)
  return __builtin_amdgcn_exp2f(x);
#else
  return exp2f(x);
#endif
}
__device__ __forceinline__ float ldval(const float* p){ return *p; }
__device__ __forceinline__ float ldval(const f16_t* p){ return (float)*p; }
__device__ __forceinline__ void stval(float* p,float v){ *p=v; }
__device__ __forceinline__ void stval(f16_t* p,float v){ *p=(f16_t)v; }
__device__ __forceinline__ h2v shxor(h2v a,int m){
  return __builtin_bit_cast(h2v,__shfl_xor(__builtin_bit_cast(int,a),m));
}

// ---------------- fused CSR build over 3 concatenated edge types ----------------
__global__ __launch_bounds__(256) void k_hist3(const int* __restrict__ dvv,const int* __restrict__ div_,
    const int* __restrict__ dvi,int* __restrict__ cnt){
  int i=blockIdx.x*256+threadIdx.x;
  if(i<E_VV) atomicAdd(&cnt[dvv[i]],1);
  else if(i<E_VV+E_IV) atomicAdd(&cnt[NV_N+div_[i-E_VV]],1);
  else atomicAdd(&cnt[2*NV_N+dvi[i-E_VV-E_IV]],1);
}
__global__ __launch_bounds__(512) void k_scan1(const int* __restrict__ cnt,int N,int* __restrict__ rp,int* __restrict__ bsum){
  __shared__ int sh[512];
  int i=blockIdx.x*512+threadIdx.x;
  int v=(i<N)?cnt[i]:0;
  sh[threadIdx.x]=v; __syncthreads();
  for(int off=1;off<512;off<<=1){
    int t=(threadIdx.x>=(unsigned)off)?sh[threadIdx.x-off]:0; __syncthreads();
    sh[threadIdx.x]+=t; __syncthreads();
  }
  if(i<N) rp[i]=sh[threadIdx.x]-v;
  if(threadIdx.x==511) bsum[blockIdx.x]=sh[511];
}
__global__ __launch_bounds__(1024) void k_scan2(const int* __restrict__ bsum,int* __restrict__ boff,int nb){
  __shared__ int sh[1024];
  int t=threadIdx.x;
  int v=(t<nb)?bsum[t]:0;
  sh[t]=v; __syncthreads();
  for(int off=1;off<1024;off<<=1){
    int x=(t>=(unsigned)off)?sh[t-off]:0; __syncthreads();
    sh[t]+=x; __syncthreads();
  }
  if(t<nb) boff[t]=sh[t]-v;
  if(t==1023) boff[nb]=sh[1023];
}
__global__ __launch_bounds__(512) void k_scan3(int* __restrict__ rp,const int* __restrict__ boff,int* __restrict__ cur,int N,int nb){
  int i=blockIdx.x*512+threadIdx.x;
  if(i<N){ int v=rp[i]+boff[i>>9]; rp[i]=v; cur[i]=v; }
  if(i==0) rp[N]=boff[nb];
}
// scatter stores PRE-SCALED source row offsets (src*stride) so the edge kernel does no mul
__global__ __launch_bounds__(256) void k_scatter3w(const int* __restrict__ svv,const int* __restrict__ dvv,
    const int* __restrict__ siv,const int* __restrict__ div_,
    const int* __restrict__ svi,const int* __restrict__ dvi,
    int* __restrict__ cur,int* __restrict__ esrc,int dlo,int dhi){
  int i=blockIdx.x*256+threadIdx.x;
  int d,s;
  if(i<E_VV){ d=dvv[i]; if(d<dlo||d>=dhi) return; s=svv[i]*320; }
  else if(i<E_VV+E_IV){ int j=i-E_VV; d=NV_N+div_[j]; if(d<dlo||d>=dhi) return; s=siv[j]*192; }
  else { int j=i-E_VV-E_IV; d=2*NV_N+dvi[j]; if(d<dlo||d>=dhi) return; s=svi[j]*320; }
  int p=atomicAdd(&cur[d],1); esrc[p]=s;
}

// initial cast: f32 inputs -> f16 x buffers
__global__ __launch_bounds__(256) void k_castx(const float* __restrict__ xi_in,const float* __restrict__ xv_in,
    f16_t* __restrict__ xi,f16_t* __restrict__ xv){
  int i=blockIdx.x*256+threadIdx.x;
  if(i<NI_N*64) xi[i]=(f16_t)xi_in[i];
  else { int j=i-NI_N*64; xv[j]=(f16_t)xv_in[j]; }
}

// ---------------- weight folding for ALL 6 layers in one launch ----------------
// k/v output columns interleaved (k_d -> base+2d, v_d -> base+2d+1) so the
// edge kernel fetches {k,v} with ONE dword load. q columns scaled by LOG2E for exp2 softmax.
struct FoldArgs{
  const float *Wk_i,*Wq_i,*Wv_i,*bk_i,*bq_i,*bv_i;
  const float *Wk_v,*Wq_v,*Wv_v,*bk_v,*bq_v,*bv_v;
  const float *arel_vv,*mrel_vv,*prel_vv,*arel_vi,*mrel_vi,*prel_vi,*arel_iv,*mrel_iv,*prel_iv;
  const float *Wa_i,*Wa_v;
  short *fwh_var,*fwl_var,*fwh_ins,*fwl_ins,*wah_i,*wal_i,*wah_v,*wal_v;
  float *fwb_var,*fwb_ins;
};
__global__ __launch_bounds__(256) void k_fold6(FoldArgs fa){
  int gid=blockIdx.x*256+threadIdx.x;
  if(gid>=6*640*64) return;
  int l=gid/(640*64);
  int rem=gid-l*640*64;
  int r=rem>>6, c=rem&63;
  if(r>=512){
    int ro=r&63;
    const float* W=(r<576)?fa.Wa_i:fa.Wa_v;
    short *sh=((r<576)?fa.wah_i:fa.wah_v)+l*4096, *sl=((r<576)?fa.wal_i:fa.wal_v)+l*4096;
    short h,lo; splitf16(W[l*4096+ro*64+c],h,lo);
    sh[ro*64+c]=h; sl[ro*64+c]=lo;
    return;
  }
  const float *W,*B,*rel=nullptr,*prl=nullptr;
  short *sh,*sl; float *fwb; int orow,d; bool isq=false;
  if(r<320){
    sh=fa.fwh_var+l*320*64; sl=fa.fwl_var+l*320*64; fwb=fa.fwb_var+l*320;
    d=r&63;
    if(r<64){ W=fa.Wq_v; B=fa.bq_v; orow=d; isq=true; }
    else if(r<128){ W=fa.Wk_v; B=fa.bk_v; rel=fa.arel_vv; prl=fa.prel_vv; orow=64+2*d; }
    else if(r<192){ W=fa.Wv_v; B=fa.bv_v; rel=fa.mrel_vv; orow=64+2*d+1; }
    else if(r<256){ W=fa.Wk_v; B=fa.bk_v; rel=fa.arel_vi; prl=fa.prel_vi; orow=192+2*d; }
    else         { W=fa.Wv_v; B=fa.bv_v; rel=fa.mrel_vi; orow=192+2*d+1; }
  }else{
    int rr=r-320; sh=fa.fwh_ins+l*192*64; sl=fa.fwl_ins+l*192*64; fwb=fa.fwb_ins+l*192;
    d=rr&63;
    if(rr<64){ W=fa.Wq_i; B=fa.bq_i; orow=d; isq=true; }
    else if(rr<128){ W=fa.Wk_i; B=fa.bk_i; rel=fa.arel_iv; prl=fa.prel_iv; orow=64+2*d; }
    else           { W=fa.Wv_i; B=fa.bv_i; rel=fa.mrel_iv; orow=64+2*d+1; }
  }
  float val,bval;
  if(!rel){
    val=W[l*4096+d*64+c]; bval=B[l*64+d];
  }else{
    int h=d>>3, e=d&7;
    float s=prl?prl[l*8+h]*0.3535533905932738f:1.0f;
    float acc=0.f,bacc=0.f;
    #pragma unroll
    for(int dd=0;dd<8;dd++){
      float rv=rel[l*512+h*64+dd*8+e];
      acc += W[l*4096+(h*8+dd)*64+c]*rv;
      bacc+= B[l*64+h*8+dd]*rv;
    }
    val=acc*s; bval=bacc*s;
  }
  if(isq){ val*=LOG2E; bval*=LOG2E; }
  short h2q,lo2; splitf16(val,h2q,lo2);
  sh[orow*64+c]=h2q; sl[orow*64+c]=lo2;
  if(c==0) fwb[orow]=bval;
}

__global__ __launch_bounds__(256) void k_split2(const float* __restrict__ W,int n,short* __restrict__ hi,short* __restrict__ lo){
  int i=blockIdx.x*256+threadIdx.x;
  if(i<n){ short h,l2; splitf16(W[i],h,l2); hi[i]=h; lo[i]=l2; }
}

// ---------------- column-resident GEMM: B frags live in registers, block grid-strides rows ----------------
__device__ __forceinline__ void colres_body(const f16_t* __restrict__ A,int nrb,
    const short* __restrict__ Bh,const short* __restrict__ Bl,
    const float* __restrict__ bias,f16_t* __restrict__ out,int octot,int ocol0,
    int c,int CH,int wave,int lane,int m,int quad,f16_t (*rep)[72])
{
  short8 bhi[4][2], blo[4][2]; float bb[4];
  #pragma unroll
  for(int ot=0;ot<4;ot++){
    size_t o=(size_t)(ocol0+ot*16+m)*64+quad*8;
    bhi[ot][0]=*(const short8*)(Bh+o);    bhi[ot][1]=*(const short8*)(Bh+o+32);
    blo[ot][0]=*(const short8*)(Bl+o);    blo[ot][1]=*(const short8*)(Bl+o+32);
    bb[ot]=bias[ocol0+ot*16+m];
  }
  int rr0=lane>>3, seg=lane&7;
  for(int rb=c;rb<nrb;rb+=CH){
    int row0=rb*64+wave*16;
    const f16_t* ap=A+(size_t)(row0+m)*64+quad*8;
    short8 a0=*(const short8*)(const void*)ap;
    short8 a1=*(const short8*)(const void*)(ap+32);
    f32x4 acc[4];
    #pragma unroll
    for(int ot=0;ot<4;ot++){ f32x4 t={bb[ot],bb[ot],bb[ot],bb[ot]}; acc[ot]=t; }
    #pragma unroll
    for(int ot=0;ot<4;ot++){
      acc[ot]=mfma16(a0,blo[ot][0],acc[ot]);
      acc[ot]=mfma16(a0,bhi[ot][0],acc[ot]);
      acc[ot]=mfma16(a1,blo[ot][1],acc[ot]);
      acc[ot]=mfma16(a1,bhi[ot][1],acc[ot]);
    }
    #pragma unroll
    for(int ot=0;ot<4;ot++)
      #pragma unroll
      for(int r=0;r<4;r++)
        rep[quad*4+r][ot*16+m]=(f16_t)acc[ot][r];
    #pragma unroll
    for(int it=0;it<2;it++){
      int rr=it*8+rr0;
      h8 vals=*(const h8*)&rep[rr][seg*8];
      *(h8*)(out+(size_t)(row0+rr)*octot+ocol0+seg*8)=vals;
    }
  }
}

// fused feature GEMM: blocks [0,5*CHV) var panels, rest ins panels
__global__ __launch_bounds__(256) void k_colres_feat(const f16_t* __restrict__ Av,const f16_t* __restrict__ Ai,
    const short* __restrict__ Bvh,const short* __restrict__ Bvl,const float* __restrict__ biasv,
    const short* __restrict__ Bih,const short* __restrict__ Bil,const float* __restrict__ biasi,
    f16_t* __restrict__ outv,f16_t* __restrict__ outi)
{
  __shared__ f16_t rep[4][16][72];
  const int wave=threadIdx.x>>6, lane=threadIdx.x&63;
  const int m=lane&15, quad=lane>>4;
  int bx=blockIdx.x;
  if(bx<5*CHV){
    int pan=bx/CHV, c=bx%CHV;
    colres_body(Av,NV_N/64,Bvh,Bvl,biasv,outv,320,pan*64,c,CHV,wave,lane,m,quad,rep[wave]);
  }else{
    bx-=5*CHV;
    int pan=bx/CHI, c=bx%CHI;
    colres_body(Ai,NI_N/64,Bih,Bil,biasi,outi,192,pan*64,c,CHI,wave,lane,m,quad,rep[wave]);
  }
}

// generic single-input column-resident GEMM (used for JK qkv)
__global__ __launch_bounds__(256) void k_colres1(const f16_t* __restrict__ A,int nrb,
    const short* __restrict__ Bh,const short* __restrict__ Bl,
    const float* __restrict__ bias,f16_t* __restrict__ out,int octot,int CH)
{
  __shared__ f16_t rep[4][16][72];
  const int wave=threadIdx.x>>6, lane=threadIdx.x&63;
  const int m=lane&15, quad=lane>>4;
  int pan=blockIdx.x/CH, c=blockIdx.x%CH;
  colres_body(A,nrb,Bh,Bl,bias,out,octot,pan*64,c,CH,wave,lane,m,quad,rep[wave]);
}

// ---------------- legacy GEMM body (float A path for osum @ Wo) ----------------
template<typename AT, typename OT>
__device__ __forceinline__ void gemm_body(const AT* __restrict__ A,int row0,
    const short* __restrict__ Bh,const short* __restrict__ Bl,
    const float* __restrict__ bias,float bias_scale,
    OT* __restrict__ out,int octot,int ocol0,int npanels,int m,int quad,int lane,
    f16_t (*rep)[72])
{
  const AT* ap=A+(size_t)(row0+m)*64+quad*8;
  constexpr bool AF16 = (sizeof(AT)==2);
  short8 ahi[2], alo[2];
  if constexpr(AF16){
    #pragma unroll
    for(int kf=0;kf<2;kf++) ahi[kf]=*(const short8*)(const void*)(ap+kf*32);
  }else{
    #pragma unroll
    for(int kf=0;kf<2;kf++){
      short8 th,tl;
      #pragma unroll
      for(int j=0;j<8;j++){ short h,l2; splitf16(ldval(&ap[kf*32+j]),h,l2); th[j]=h; tl[j]=l2; }
      ahi[kf]=th; alo[kf]=tl;
    }
  }
  for(int pan=0;pan<npanels;pan++){
    int colbase=pan*64;
    short8 bhi[4][2], blo[4][2];
    #pragma unroll
    for(int ot=0;ot<4;ot++){
      size_t o=(size_t)(colbase+ot*16+m)*64+quad*8;
      #pragma unroll
      for(int kf=0;kf<2;kf++){
        bhi[ot][kf]=*(const short8*)(Bh+o+kf*32);
        blo[ot][kf]=*(const short8*)(Bl+o+kf*32);
      }
    }
    f32x4 acc[4];
    #pragma unroll
    for(int ot=0;ot<4;ot++){
      float bv=bias[colbase+ot*16+m]*bias_scale;
      acc[ot][0]=bv; acc[ot][1]=bv; acc[ot][2]=bv; acc[ot][3]=bv;
    }
    #pragma unroll
    for(int ot=0;ot<4;ot++){
      #pragma unroll
      for(int kf=0;kf<2;kf++){
        if constexpr(!AF16) acc[ot]=mfma16(alo[kf],bhi[ot][kf],acc[ot]);
        acc[ot]=mfma16(ahi[kf],blo[ot][kf],acc[ot]);
        acc[ot]=mfma16(ahi[kf],bhi[ot][kf],acc[ot]);
      }
    }
    if constexpr(sizeof(OT)==2){
      #pragma unroll
      for(int ot=0;ot<4;ot++)
        #pragma unroll
        for(int r=0;r<4;r++)
          rep[quad*4+r][ot*16+m]=(f16_t)acc[ot][r];
      #pragma unroll
      for(int it=0;it<2;it++){
        int rr=it*8+(lane>>3), seg=lane&7;
        h8 vals=*(const h8*)&rep[rr][seg*8];
        *(h8*)(out+(size_t)(row0+rr)*octot+ocol0+colbase+seg*8)=vals;
      }
    }else{
      #pragma unroll
      for(int ot=0;ot<4;ot++){
        int col=ocol0+colbase+ot*16+m;
        #pragma unroll
        for(int r=0;r<4;r++){
          int row=row0+quad*4+r;
          stval(&out[(size_t)row*octot+col],acc[ot][r]);
        }
      }
    }
  }
}

template<typename AT, typename OT>
__global__ __launch_bounds__(256) void k_gemm64p(const AT* __restrict__ A,int N,
    const short* __restrict__ Bh,const short* __restrict__ Bl,
    const float* __restrict__ bias,float bias_scale,
    OT* __restrict__ out,int octot,int ocol0,int npanels)
{
  __shared__ f16_t rep[4][16][72];
  const int wave=threadIdx.x>>6, lane=threadIdx.x&63;
  const int m=lane&15, quad=lane>>4;
  const int row0=blockIdx.x*64+wave*16;
  if(row0>=N) return;
  gemm_body<AT,OT>(A,row0,Bh,Bl,bias,bias_scale,out,octot,ocol0,npanels,m,quad,lane,rep[wave]);
}

// ---------------- fused per-layer update (instr blocks then var blocks), x/agg f16, LDS-repacked I/O ----------------
__global__ __launch_bounds__(256) void k_update2(const f16_t* __restrict__ agg_i,const f16_t* __restrict__ agg_v,
    const short* __restrict__ wah_i,const short* __restrict__ wal_i,
    const short* __restrict__ wah_v,const short* __restrict__ wal_v,
    const float* __restrict__ ba_i,const float* __restrict__ ba_v,
    const float* __restrict__ skip_i,const float* __restrict__ skip_v,
    f16_t* __restrict__ x_i,f16_t* __restrict__ x_v,
    f16_t* __restrict__ outs,int nbi)
{
  __shared__ f16_t rep[4][16][72];
  const int wave=threadIdx.x>>6, lane=threadIdx.x&63;
  const int m=lane&15, quad=lane>>4;
  const bool isI=(int)blockIdx.x<nbi;
  const int row0=(isI?blockIdx.x:(blockIdx.x-nbi))*64+wave*16;
  const f16_t* agg=isI?agg_i:agg_v;
  const short* Wah=isI?wah_i:wah_v;
  const short* Wal=isI?wal_i:wal_v;
  const float* ba=isI?ba_i:ba_v;
  const float* skip=isI?skip_i:skip_v;
  f16_t* x=isI?x_i:x_v;
  f16_t* oo=isI?outs:nullptr;
  f16_t (*R)[72]=rep[wave];
  short8 bhi[4][2], blo[4][2];
  #pragma unroll
  for(int ot=0;ot<4;ot++){
    size_t o=(size_t)(ot*16+m)*64+quad*8;
    #pragma unroll
    for(int kf=0;kf<2;kf++){
      bhi[ot][kf]=*(const short8*)(Wah+o+kf*32);
      blo[ot][kf]=*(const short8*)(Wal+o+kf*32);
    }
  }
  const f16_t* ap=agg+(size_t)(row0+m)*64+quad*8;
  short8 ahi[2], alo[2];
  #pragma unroll
  for(int kf=0;kf<2;kf++){
    short8 th,tl;
    #pragma unroll
    for(int j=0;j<8;j++){ short h,l2; splitf16(gelu_f((float)ap[kf*32+j]),h,l2); th[j]=h; tl[j]=l2; }
    ahi[kf]=th; alo[kf]=tl;
  }
  // stage x rows into LDS (wide loads)
  int rr0=lane>>3, seg=lane&7;
  h8 x0=*(const h8*)(x+(size_t)(row0+rr0)*64+seg*8);
  h8 x1=*(const h8*)(x+(size_t)(row0+8+rr0)*64+seg*8);
  *(h8*)&R[rr0][seg*8]=x0;
  *(h8*)&R[8+rr0][seg*8]=x1;
  f32x4 acc[4];
  #pragma unroll
  for(int ot=0;ot<4;ot++){
    float bv=ba[ot*16+m];
    acc[ot][0]=bv; acc[ot][1]=bv; acc[ot][2]=bv; acc[ot][3]=bv;
  }
  #pragma unroll
  for(int ot=0;ot<4;ot++){
    #pragma unroll
    for(int kf=0;kf<2;kf++){
      acc[ot]=mfma16(alo[kf],bhi[ot][kf],acc[ot]);
      acc[ot]=mfma16(ahi[kf],blo[ot][kf],acc[ot]);
      acc[ot]=mfma16(ahi[kf],bhi[ot][kf],acc[ot]);
    }
  }
  float s=1.0f/(1.0f+__expf(-skip[0]));
  #pragma unroll
  for(int ot=0;ot<4;ot++){
    int col=ot*16+m;
    #pragma unroll
    for(int r=0;r<4;r++){
      int row=quad*4+r;
      float xn=s*acc[ot][r]+(1.0f-s)*(float)R[row][col];
      R[row][col]=(f16_t)xn;
    }
  }
  h8 o0=*(const h8*)&R[rr0][seg*8];
  h8 o1=*(const h8*)&R[8+rr0][seg*8];
  *(h8*)(x+(size_t)(row0+rr0)*64+seg*8)=o0;
  *(h8*)(x+(size_t)(row0+8+rr0)*64+seg*8)=o1;
  if(oo){
    *(h8*)(oo+(size_t)(row0+rr0)*64+seg*8)=o0;
    *(h8*)(oo+(size_t)(row0+8+rr0)*64+seg*8)=o1;
  }
}

// ---------------- edge attention: lane = feature dim, 8-edge predicated batch ----------------
// esrc holds PRE-SCALED row offsets (src*stride). kv interleaved: k at koff+2d, v at +1.
// logits pre-scaled by LOG2E -> exp2.
__device__ __forceinline__ float edge_agg8(const int* __restrict__ rp,const int* __restrict__ es,
    const f16_t* __restrict__ sf,int koff,int n,int lane,f16_t qh)
{
  int b=__builtin_amdgcn_readfirstlane(rp[n]);
  int e=__builtin_amdgcn_readfirstlane(rp[n+1]);
  if(b==e) return 0.f;
  float m=-INFINITY, ls=0.f, acc=0.f;
  h2v q2={qh,qh};
  const int lo2=koff+2*lane;
  for(int i=b;i<e;i+=8){
    int o[8];
    #pragma unroll
    for(int j=0;j<8;j++){
      int idx=i+j; idx=(idx<e)?idx:(e-1);
      o[j]=__builtin_amdgcn_readfirstlane(es[idx]);
    }
    h2v kv[8];
    #pragma unroll
    for(int j=0;j<8;j++) kv[j]=*(const h2v*)(sf+(size_t)(unsigned)o[j]+lo2);
    float p[8];
    #pragma unroll
    for(int jp=0;jp<4;jp++){
      h2v pa={kv[2*jp][0],kv[2*jp+1][0]};
      pa=q2*pa;
      pa=pa+shxor(pa,1);
      pa=pa+shxor(pa,2);
      pa=pa+shxor(pa,4);
      p[2*jp]=(float)pa[0]; p[2*jp+1]=(float)pa[1];
    }
    #pragma unroll
    for(int j=0;j<8;j++) p[j]=(i+j<e)?p[j]:-INFINITY;
    float t0=fmaxf(p[0],p[1]),t1=fmaxf(p[2],p[3]),t2=fmaxf(p[4],p[5]),t3=fmaxf(p[6],p[7]);
    float mn=fmaxf(fmaxf(fmaxf(t0,t1),fmaxf(t2,t3)),m);
    float sc=fexp2(m-mn);            // first iter: exp2(-inf)=0
    float w[8];
    #pragma unroll
    for(int j=0;j<8;j++) w[j]=fexp2(p[j]-mn);
    float sw=((w[0]+w[1])+(w[2]+w[3]))+((w[4]+w[5])+(w[6]+w[7]));
    float sa=w[0]*(float)kv[0][1]; sa=fmaf(w[1],(float)kv[1][1],sa);
    float sb=w[2]*(float)kv[2][1]; sb=fmaf(w[3],(float)kv[3][1],sb);
    float sg=w[4]*(float)kv[4][1]; sg=fmaf(w[5],(float)kv[5][1],sg);
    float sd=w[6]*(float)kv[6][1]; sd=fmaf(w[7],(float)kv[7][1],sd);
    ls=fmaf(ls,sc,sw);
    acc=fmaf(acc,sc,(sa+sb)+(sg+sd));
    m=mn;
  }
  return acc/(ls+1e-16f);   // degree 0 -> 0, matches PyG semantics
}

// fused edge kernel: blocks [0,nbv) var destinations (vv+iv), rest instr destinations (vi)
__global__ __launch_bounds__(256) void k_edge_all(const int* __restrict__ rp_all,const int* __restrict__ es,
    const f16_t* __restrict__ var_feat,const f16_t* __restrict__ ins_feat,
    f16_t* __restrict__ agg_v,f16_t* __restrict__ agg_i,int nbv)
{
  int wave=threadIdx.x>>6, lane=threadIdx.x&63;
  if((int)blockIdx.x<nbv){
    int n=blockIdx.x*4+wave;
    f16_t qh=var_feat[(size_t)n*320+lane];
    float r1=edge_agg8(rp_all,es,var_feat,64,n,lane,qh);
    float r2=edge_agg8(rp_all+NV_N,es,ins_feat,64,n,lane,qh);
    agg_v[(size_t)n*64+lane]=(f16_t)(r1+r2);
  }else{
    int n=(blockIdx.x-nbv)*4+wave;
    f16_t qh=ins_feat[(size_t)n*192+lane];
    float r=edge_agg8(rp_all+2*NV_N,es,var_feat,192,n,lane,qh);
    agg_i[(size_t)n*64+lane]=(f16_t)r;
  }
}

// ---------------- jumping-knowledge 5x5 attention, one wave per node
__global__ __launch_bounds__(256) void k_jk(const f16_t* __restrict__ qkv,float* __restrict__ osum,int n_nodes){
  int wave=threadIdx.x>>6, lane=threadIdx.x&63;
  int n=blockIdx.x*4+wave;
  if(n>=n_nodes) return;
  float q[5],k[5],v[5];
  #pragma unroll
  for(int s=0;s<5;s++){
    const f16_t* p=qkv+((size_t)s*n_nodes+n)*192;
    q[s]=(float)p[lane]; k[s]=(float)p[64+lane]; v[s]=(float)p[128+lane];
  }
  float sc[5][5];
  #pragma unroll
  for(int s=0;s<5;s++)
    #pragma unroll
    for(int t=0;t<5;t++){
      float x=q[s]*k[t];
      x+=__shfl_xor(x,1); x+=__shfl_xor(x,2); x+=__shfl_xor(x,4);
      sc[s][t]=x*0.3535533905932738f;
    }
  float os=0.f;
  #pragma unroll
  for(int s=0;s<5;s++){
    float m=sc[s][0];
    #pragma unroll
    for(int t=1;t<5;t++) m=fmaxf(m,sc[s][t]);
    float den=0.f, acc=0.f;
    #pragma unroll
    for(int t=0;t<5;t++){ float e=__expf(sc[s][t]-m); den+=e; acc+=e*v[t]; }
    os+=acc/den;
  }
  osum[(size_t)n*64+lane]=os;
}

// ---------------- MLP head ----------------
struct MlpArgs{ const float *w0,*b0,*w1,*b1,*w2,*b2,*w3,*b3,*w4,*b4,*w5,*b5; };
__global__ __launch_bounds__(256) void k_mlp(const float* __restrict__ in,MlpArgs ma,float* __restrict__ out,int N){
  __shared__ float sw0[2048],sb0[32],sw1[512],sb1[16],sw2[128],sb2[8],sw3[32],sb3[4],sw4[8],sb4[2],sw5[2],sb5[1];
  for(int i=threadIdx.x;i<2048;i+=256) sw0[i]=ma.w0[i];
  for(int i=threadIdx.x;i<512;i+=256)  sw1[i]=ma.w1[i];
  if(threadIdx.x<128) sw2[threadIdx.x]=ma.w2[threadIdx.x];
  if(threadIdx.x<32){ sb0[threadIdx.x]=ma.b0[threadIdx.x]; sw3[threadIdx.x]=ma.w3[threadIdx.x]; }
  if(threadIdx.x<16) sb1[threadIdx.x]=ma.b1[threadIdx.x];
  if(threadIdx.x<8){ sb2[threadIdx.x]=ma.b2[threadIdx.x]; sw4[threadIdx.x]=ma.w4[threadIdx.x]; }
  if(threadIdx.x<4) sb3[threadIdx.x]=ma.b3[threadIdx.x];
  if(threadIdx.x<2){ sb4[threadIdx.x]=ma.b4[threadIdx.x]; sw5[threadIdx.x]=ma.w5[threadIdx.x]; }
  if(threadIdx.x==0) sb5[0]=ma.b5[0];
  __syncthreads();
  int n=blockIdx.x*256+threadIdx.x;
  if(n>=N) return;
  float a[64];
  const f32x4* p4=(const f32x4*)(in+(size_t)n*64);
  #pragma unroll
  for(int j=0;j<16;j++){ f32x4 t=p4[j]; a[4*j]=t[0]; a[4*j+1]=t[1]; a[4*j+2]=t[2]; a[4*j+3]=t[3]; }
  float h1[32];
  #pragma unroll
  for(int o=0;o<32;o++){ float s=sb0[o];
    #pragma unroll
    for(int c=0;c<64;c++) s+=a[c]*sw0[o*64+c];
    h1[o]=gelu_f(s); }
  float h2q[16];
  #pragma unroll
  for(int o=0;o<16;o++){ float s=sb1[o];
    #pragma unroll
    for(int c=0;c<32;c++) s+=h1[c]*sw1[o*32+c];
    h2q[o]=gelu_f(s); }
  float h3[8];
  #pragma unroll
  for(int o=0;o<8;o++){ float s=sb2[o];
    #pragma unroll
    for(int c=0;c<16;c++) s+=h2q[c]*sw2[o*16+c];
    h3[o]=gelu_f(s); }
  float h4[4];
  #pragma unroll
  for(int o=0;o<4;o++){ float s=sb3[o];
    #pragma unroll
    for(int c=0;c<8;c++) s+=h3[c]*sw3[o*8+c];
    h4[o]=gelu_f(s); }
  float h5[2];
  #pragma unroll
  for(int o=0;o<2;o++){ float s=sb4[o];
    #pragma unroll
    for(int c=0;c<4;c++) s+=h4[c]*sw4[o*4+c];
    h5[o]=gelu_f(s); }
  float r=sb5[0]+h5[0]*sw5[0]+h5[1]*sw5[1];
  out[n]=r;
}

// ================= host launcher =================
extern "C" void kernel_launch(void* const* d_in,const int* in_sizes,int n_in,
                              void* d_out,int out_size,void* d_ws,size_t ws_size,
                              hipStream_t stream){
  (void)in_sizes;(void)n_in;(void)out_size;(void)ws_size;
  const float* x_instr=(const float*)d_in[0];
  const float* x_var  =(const float*)d_in[1];
  const float* ba_i=(const float*)d_in[9];
  const float* skip_i=(const float*)d_in[10];
  const float* ba_v=(const float*)d_in[18];
  const float* skip_v=(const float*)d_in[19];
  const float* Wqkv=(const float*)d_in[29];
  const float* bqkv=(const float*)d_in[30];
  const float* Wo=(const float*)d_in[31];
  const float* bo=(const float*)d_in[32];
  const int* src_vv=(const int*)d_in[45];
  const int* dst_vv=(const int*)d_in[46];
  const int* src_vi=(const int*)d_in[47];
  const int* dst_vi=(const int*)d_in[48];
  const int* src_iv=(const int*)d_in[49];
  const int* dst_iv=(const int*)d_in[50];

  char* w=(char*)d_ws;
  auto alloc=[&](size_t b)->char*{ char* p=w; w+=(b+255)&~(size_t)255; return p; };
  // ---- fused CSR arrays (~12 MB) ----
  int* rp_all=(int*)alloc((size_t)(NT_N+1)*4);
  int* cnt_all=(int*)alloc((size_t)NT_N*4);
  int* cur_all=(int*)alloc((size_t)NT_N*4);
  int* bsum =(int*)alloc(640*4);
  int* boff =(int*)alloc(640*4);
  int* esrc_all=(int*)alloc((size_t)ET_N*4);
  // ---- folded + pre-split weights for all 6 layers (~2.5 MB) ----
  short* fwh_var=(short*)alloc((size_t)6*320*64*2);
  short* fwl_var=(short*)alloc((size_t)6*320*64*2);
  float* fwb_var=(float*)alloc((size_t)6*320*4);
  short* fwh_ins=(short*)alloc((size_t)6*192*64*2);
  short* fwl_ins=(short*)alloc((size_t)6*192*64*2);
  float* fwb_ins=(float*)alloc((size_t)6*192*4);
  short* wah_i=(short*)alloc((size_t)6*64*64*2);
  short* wal_i=(short*)alloc((size_t)6*64*64*2);
  short* wah_v=(short*)alloc((size_t)6*64*64*2);
  short* wal_v=(short*)alloc((size_t)6*64*64*2);
  short* qkvh=(short*)alloc(192*64*2);
  short* qkvl=(short*)alloc(192*64*2);
  short* woh=(short*)alloc(64*64*2);
  short* wol=(short*)alloc(64*64*2);
  // ---- persistent across phases: outs (f16, 21 MB) ----
  f16_t* outs=(f16_t*)alloc((size_t)5*NI_N*64*2);
  // ---- arena (140 MB), phase-overlaid ----
  char* arena=alloc((size_t)146800640);
  f16_t*  xv      =(f16_t*)(arena);                                // 16,777,216 B
  f16_t*  xi      =(f16_t*)(arena+16777216);                       //  4,194,304 B
  f16_t*  var_feat=(f16_t*)(arena+20971520);                       // 83,886,080 B (stride 320: q | kv_vv interleaved | kv_vi interleaved)
  f16_t*  ins_feat=(f16_t*)(arena+104857600);                      // 12,582,912 B (stride 192: q | kv interleaved)
  f16_t*  agg_v   =(f16_t*)(arena+117440512);                      // 16,777,216 B
  f16_t*  agg_i   =(f16_t*)(arena+134217728);                      //  4,194,304 B
  // JK phase overlays (xv/xi/var_feat dead by then):
  f16_t*  qkv    =(f16_t*)(arena);                                 // 62,914,560 B
  float*  osum   =(float*)(arena+67108864);                        //  8,388,608 B (inside dead var_feat)
  float*  out_jk =(float*)(arena+75497472);                        //  8,388,608 B (inside dead var_feat)

  // fused CSR build
  hipMemsetAsync(cnt_all,0,(size_t)NT_N*4,stream);
  k_hist3<<<ET_N/256,256,0,stream>>>(dst_vv,dst_iv,dst_vi,cnt_all);
  int nb=NT_N/512;   // 576
  k_scan1<<<nb,512,0,stream>>>(cnt_all,NT_N,rp_all,bsum);
  k_scan2<<<1,1024,0,stream>>>(bsum,boff,nb);
  k_scan3<<<nb,512,0,stream>>>(rp_all,boff,cur_all,NT_N,nb);
  for(int wdx=0;wdx<SC_WIN;wdx++){
    int dlo=wdx*(NT_N/SC_WIN), dhi=(wdx+1)*(NT_N/SC_WIN);
    k_scatter3w<<<ET_N/256,256,0,stream>>>(src_vv,dst_vv,src_iv,dst_iv,src_vi,dst_vi,cur_all,esrc_all,dlo,dhi);
  }

  k_castx<<<(NI_N*64+NV_N*64)/256,256,0,stream>>>(x_instr,x_var,xi,xv);

  // one-time splits for JK weights
  k_split2<<<(192*64+255)/256,256,0,stream>>>(Wqkv,192*64,qkvh,qkvl);
  k_split2<<<(64*64+255)/256,256,0,stream>>>(Wo,64*64,woh,wol);

  FoldArgs fa;
  fa.Wk_i=(const float*)d_in[2]; fa.Wq_i=(const float*)d_in[3]; fa.Wv_i=(const float*)d_in[4];
  fa.bk_i=(const float*)d_in[6]; fa.bq_i=(const float*)d_in[7]; fa.bv_i=(const float*)d_in[8];
  fa.Wk_v=(const float*)d_in[11]; fa.Wq_v=(const float*)d_in[12]; fa.Wv_v=(const float*)d_in[13];
  fa.bk_v=(const float*)d_in[15]; fa.bq_v=(const float*)d_in[16]; fa.bv_v=(const float*)d_in[17];
  fa.arel_vv=(const float*)d_in[20]; fa.mrel_vv=(const float*)d_in[21]; fa.prel_vv=(const float*)d_in[22];
  fa.arel_vi=(const float*)d_in[23]; fa.mrel_vi=(const float*)d_in[24]; fa.prel_vi=(const float*)d_in[25];
  fa.arel_iv=(const float*)d_in[26]; fa.mrel_iv=(const float*)d_in[27]; fa.prel_iv=(const float*)d_in[28];
  fa.Wa_i=(const float*)d_in[5]; fa.Wa_v=(const float*)d_in[14];
  fa.fwh_var=fwh_var; fa.fwl_var=fwl_var; fa.fwh_ins=fwh_ins; fa.fwl_ins=fwl_ins;
  fa.wah_i=wah_i; fa.wal_i=wal_i; fa.wah_v=wah_v; fa.wal_v=wal_v;
  fa.fwb_var=fwb_var; fa.fwb_ins=fwb_ins;
  k_fold6<<<(6*640*64)/256,256,0,stream>>>(fa);

  for(int l=0;l<6;l++){
    k_colres_feat<<<5*CHV+3*CHI,256,0,stream>>>(xv,xi,
        fwh_var+(size_t)l*320*64,fwl_var+(size_t)l*320*64,fwb_var+l*320,
        fwh_ins+(size_t)l*192*64,fwl_ins+(size_t)l*192*64,fwb_ins+l*192,
        var_feat,ins_feat);
    k_edge_all<<<NV_N/4+NI_N/4,256,0,stream>>>(rp_all,esrc_all,var_feat,ins_feat,agg_v,agg_i,NV_N/4);
    k_update2<<<NI_N/64+NV_N/64,256,0,stream>>>(agg_i,agg_v,
        wah_i+(size_t)l*4096,wal_i+(size_t)l*4096,wah_v+(size_t)l*4096,wal_v+(size_t)l*4096,
        ba_i+l*64,ba_v+l*64,skip_i+l,skip_v+l,xi,xv,
        (l>0)?(outs+(size_t)(l-1)*NI_N*64):nullptr,NI_N/64);
  }

  // jumping knowledge + head
  k_colres1<<<3*CHQ,256,0,stream>>>(outs,5*NI_N/64,qkvh,qkvl,bqkv,qkv,192,CHQ);
  k_jk<<<NI_N/4,256,0,stream>>>(qkv,osum,NI_N);
  k_gemm64p<float,float><<<NI_N/64,256,0,stream>>>(osum,NI_N,woh,wol,bo,5.0f,out_jk,64,0,1);
  MlpArgs ma;
  ma.w0=(const float*)d_in[33]; ma.b0=(const float*)d_in[34];
  ma.w1=(const float*)d_in[35]; ma.b1=(const float*)d_in[36];
  ma.w2=(const float*)d_in[37]; ma.b2=(const float*)d_in[38];
  ma.w3=(const float*)d_in[39]; ma.b3=(const float*)d_in[40];
  ma.w4=(const float*)d_in[41]; ma.b4=(const float*)d_in[42];
  ma.w5=(const float*)d_in[43]; ma.b5=(const float*)d_in[44];
  k_mlp<<<NI_N/256,256,0,stream>>>(out_jk,ma,(float*)d_out,NI_N);
}

// Round 5
// 1528.937 us; speedup vs baseline: 1.3661x; 1.0699x over previous
//
#include <hip/hip_runtime.h>
#include <cmath>

typedef _Float16 f16_t;                                         // IEEE fp16
typedef __attribute__((ext_vector_type(8))) short short8;       // MFMA A/B frag (bit container)
typedef __attribute__((ext_vector_type(8))) _Float16 half8;     // MFMA f16 frag
typedef __attribute__((ext_vector_type(4))) float f32x4;        // MFMA C/D frag
typedef _Float16 h2v __attribute__((ext_vector_type(2)));       // packed f16 pair
typedef _Float16 h8 __attribute__((ext_vector_type(8)));        // 16B f16 vector
typedef float f2 __attribute__((ext_vector_type(2)));           // packed f32 pair

#define NI_N 32768
#define NV_N 131072
#define E_VV 1048576
#define E_VI 524288
#define E_IV 524288
#define NT_N (NV_N+NV_N+NI_N)          // 294912 concatenated nodes (vv|iv|vi)
#define ET_N (E_VV+E_IV+E_VI)          // 2097152 concatenated edges
#define SC_WIN 4                        // scatter windows
#define LOG2E 1.4426950408889634f
#define CHV 192                         // row-chunks per var panel (colres)
#define CHI 64                          // row-chunks per ins panel
#define CHQ 256                         // row-chunks per qkv panel

__device__ __forceinline__ float gelu_f(float x){ return 0.5f*x*(1.0f+erff(x*0.7071067811865476f)); }

// split f32 into hi/lo f16 (hi+lo carries ~22 bits of mantissa)
__device__ __forceinline__ void splitf16(float v, short& hi, short& lo){
  f16_t h=(f16_t)v;
  hi=__builtin_bit_cast(short,h);
  f16_t l=(f16_t)(v-(float)h);
  lo=__builtin_bit_cast(short,l);
}
__device__ __forceinline__ f32x4 mfma16(short8 a, short8 b, f32x4 c){
  return __builtin_amdgcn_mfma_f32_16x16x32_f16(__builtin_bit_cast(half8,a),__builtin_bit_cast(half8,b),c,0,0,0);
}
__device__ __forceinline__ float fexp2(float x){
#if __has_builtin(__builtin_amdgcn_exp2f)
  return __builtin_amdgcn_exp2f(x);
#else
  return exp2f(x);
#endif
}
__device__ __forceinline__ float ldval(const float* p){ return *p; }
__device__ __forceinline__ float ldval(const f16_t* p){ return (float)*p; }
__device__ __forceinline__ void stval(float* p,float v){ *p=v; }
__device__ __forceinline__ void stval(f16_t* p,float v){ *p=(f16_t)v; }

// ---------------- fused CSR build over 3 concatenated edge types ----------------
__global__ __launch_bounds__(256) void k_hist3(const int* __restrict__ dvv,const int* __restrict__ div_,
    const int* __restrict__ dvi,int* __restrict__ cnt){
  int i=blockIdx.x*256+threadIdx.x;
  if(i<E_VV) atomicAdd(&cnt[dvv[i]],1);
  else if(i<E_VV+E_IV) atomicAdd(&cnt[NV_N+div_[i-E_VV]],1);
  else atomicAdd(&cnt[2*NV_N+dvi[i-E_VV-E_IV]],1);
}
__global__ __launch_bounds__(512) void k_scan1(const int* __restrict__ cnt,int N,int* __restrict__ rp,int* __restrict__ bsum){
  __shared__ int sh[512];
  int i=blockIdx.x*512+threadIdx.x;
  int v=(i<N)?cnt[i]:0;
  sh[threadIdx.x]=v; __syncthreads();
  for(int off=1;off<512;off<<=1){
    int t=(threadIdx.x>=(unsigned)off)?sh[threadIdx.x-off]:0; __syncthreads();
    sh[threadIdx.x]+=t; __syncthreads();
  }
  if(i<N) rp[i]=sh[threadIdx.x]-v;
  if(threadIdx.x==511) bsum[blockIdx.x]=sh[511];
}
__global__ __launch_bounds__(1024) void k_scan2(const int* __restrict__ bsum,int* __restrict__ boff,int nb){
  __shared__ int sh[1024];
  int t=threadIdx.x;
  int v=(t<nb)?bsum[t]:0;
  sh[t]=v; __syncthreads();
  for(int off=1;off<1024;off<<=1){
    int x=(t>=(unsigned)off)?sh[t-off]:0; __syncthreads();
    sh[t]+=x; __syncthreads();
  }
  if(t<nb) boff[t]=sh[t]-v;
  if(t==1023) boff[nb]=sh[1023];
}
__global__ __launch_bounds__(512) void k_scan3(int* __restrict__ rp,const int* __restrict__ boff,int* __restrict__ cur,int N,int nb){
  int i=blockIdx.x*512+threadIdx.x;
  if(i<N){ int v=rp[i]+boff[i>>9]; rp[i]=v; cur[i]=v; }
  if(i==0) rp[N]=boff[nb];
}
// scatter stores PRE-SCALED source row offsets (src*stride) so the edge kernel does no mul
__global__ __launch_bounds__(256) void k_scatter3w(const int* __restrict__ svv,const int* __restrict__ dvv,
    const int* __restrict__ siv,const int* __restrict__ div_,
    const int* __restrict__ svi,const int* __restrict__ dvi,
    int* __restrict__ cur,int* __restrict__ esrc,int dlo,int dhi){
  int i=blockIdx.x*256+threadIdx.x;
  int d,s;
  if(i<E_VV){ d=dvv[i]; if(d<dlo||d>=dhi) return; s=svv[i]*320; }
  else if(i<E_VV+E_IV){ int j=i-E_VV; d=NV_N+div_[j]; if(d<dlo||d>=dhi) return; s=siv[j]*192; }
  else { int j=i-E_VV-E_IV; d=2*NV_N+dvi[j]; if(d<dlo||d>=dhi) return; s=svi[j]*320; }
  int p=atomicAdd(&cur[d],1); esrc[p]=s;
}

// initial cast: f32 inputs -> f16 x buffers
__global__ __launch_bounds__(256) void k_castx(const float* __restrict__ xi_in,const float* __restrict__ xv_in,
    f16_t* __restrict__ xi,f16_t* __restrict__ xv){
  int i=blockIdx.x*256+threadIdx.x;
  if(i<NI_N*64) xi[i]=(f16_t)xi_in[i];
  else { int j=i-NI_N*64; xv[j]=(f16_t)xv_in[j]; }
}

// ---------------- weight folding for ALL 6 layers in one launch ----------------
// Contiguous block layout: q(64) | k(64) | v(64) [| k2 | v2] so the edge kernel
// loads per-head 16B k-rows and v-rows. q columns scaled by LOG2E for exp2 softmax.
struct FoldArgs{
  const float *Wk_i,*Wq_i,*Wv_i,*bk_i,*bq_i,*bv_i;
  const float *Wk_v,*Wq_v,*Wv_v,*bk_v,*bq_v,*bv_v;
  const float *arel_vv,*mrel_vv,*prel_vv,*arel_vi,*mrel_vi,*prel_vi,*arel_iv,*mrel_iv,*prel_iv;
  const float *Wa_i,*Wa_v;
  short *fwh_var,*fwl_var,*fwh_ins,*fwl_ins,*wah_i,*wal_i,*wah_v,*wal_v;
  float *fwb_var,*fwb_ins;
};
__global__ __launch_bounds__(256) void k_fold6(FoldArgs fa){
  int gid=blockIdx.x*256+threadIdx.x;
  if(gid>=6*640*64) return;
  int l=gid/(640*64);
  int rem=gid-l*640*64;
  int r=rem>>6, c=rem&63;
  if(r>=512){
    int ro=r&63;
    const float* W=(r<576)?fa.Wa_i:fa.Wa_v;
    short *sh=((r<576)?fa.wah_i:fa.wah_v)+l*4096, *sl=((r<576)?fa.wal_i:fa.wal_v)+l*4096;
    short h,lo; splitf16(W[l*4096+ro*64+c],h,lo);
    sh[ro*64+c]=h; sl[ro*64+c]=lo;
    return;
  }
  const float *W,*B,*rel=nullptr,*prl=nullptr;
  short *sh,*sl; float *fwb; int orow; bool isq=false;
  if(r<320){
    sh=fa.fwh_var+l*320*64; sl=fa.fwl_var+l*320*64; fwb=fa.fwb_var+l*320; orow=r;
    if(r<64){ W=fa.Wq_v; B=fa.bq_v; isq=true; }
    else if(r<128){ W=fa.Wk_v; B=fa.bk_v; rel=fa.arel_vv; prl=fa.prel_vv; }
    else if(r<192){ W=fa.Wv_v; B=fa.bv_v; rel=fa.mrel_vv; }
    else if(r<256){ W=fa.Wk_v; B=fa.bk_v; rel=fa.arel_vi; prl=fa.prel_vi; }
    else         { W=fa.Wv_v; B=fa.bv_v; rel=fa.mrel_vi; }
  }else{
    int rr=r-320; sh=fa.fwh_ins+l*192*64; sl=fa.fwl_ins+l*192*64; fwb=fa.fwb_ins+l*192; orow=rr;
    if(rr<64){ W=fa.Wq_i; B=fa.bq_i; isq=true; }
    else if(rr<128){ W=fa.Wk_i; B=fa.bk_i; rel=fa.arel_iv; prl=fa.prel_iv; }
    else           { W=fa.Wv_i; B=fa.bv_i; rel=fa.mrel_iv; }
  }
  int d=orow&63;
  float val,bval;
  if(!rel){
    val=W[l*4096+d*64+c]; bval=B[l*64+d];
  }else{
    int h=d>>3, e=d&7;
    float s=prl?prl[l*8+h]*0.3535533905932738f:1.0f;
    float acc=0.f,bacc=0.f;
    #pragma unroll
    for(int dd=0;dd<8;dd++){
      float rv=rel[l*512+h*64+dd*8+e];
      acc += W[l*4096+(h*8+dd)*64+c]*rv;
      bacc+= B[l*64+h*8+dd]*rv;
    }
    val=acc*s; bval=bacc*s;
  }
  if(isq){ val*=LOG2E; bval*=LOG2E; }
  short h2q,lo2; splitf16(val,h2q,lo2);
  sh[orow*64+c]=h2q; sl[orow*64+c]=lo2;
  if(c==0) fwb[orow]=bval;
}

__global__ __launch_bounds__(256) void k_split2(const float* __restrict__ W,int n,short* __restrict__ hi,short* __restrict__ lo){
  int i=blockIdx.x*256+threadIdx.x;
  if(i<n){ short h,l2; splitf16(W[i],h,l2); hi[i]=h; lo[i]=l2; }
}

// ---------------- column-resident GEMM: B frags live in registers, block grid-strides rows ----------------
__device__ __forceinline__ void colres_body(const f16_t* __restrict__ A,int nrb,
    const short* __restrict__ Bh,const short* __restrict__ Bl,
    const float* __restrict__ bias,f16_t* __restrict__ out,int octot,int ocol0,
    int c,int CH,int wave,int lane,int m,int quad,f16_t (*rep)[72])
{
  short8 bhi[4][2], blo[4][2]; float bb[4];
  #pragma unroll
  for(int ot=0;ot<4;ot++){
    size_t o=(size_t)(ocol0+ot*16+m)*64+quad*8;
    bhi[ot][0]=*(const short8*)(Bh+o);    bhi[ot][1]=*(const short8*)(Bh+o+32);
    blo[ot][0]=*(const short8*)(Bl+o);    blo[ot][1]=*(const short8*)(Bl+o+32);
    bb[ot]=bias[ocol0+ot*16+m];
  }
  int rr0=lane>>3, seg=lane&7;
  for(int rb=c;rb<nrb;rb+=CH){
    int row0=rb*64+wave*16;
    const f16_t* ap=A+(size_t)(row0+m)*64+quad*8;
    short8 a0=*(const short8*)(const void*)ap;
    short8 a1=*(const short8*)(const void*)(ap+32);
    f32x4 acc[4];
    #pragma unroll
    for(int ot=0;ot<4;ot++){ f32x4 t={bb[ot],bb[ot],bb[ot],bb[ot]}; acc[ot]=t; }
    #pragma unroll
    for(int ot=0;ot<4;ot++){
      acc[ot]=mfma16(a0,blo[ot][0],acc[ot]);
      acc[ot]=mfma16(a0,bhi[ot][0],acc[ot]);
      acc[ot]=mfma16(a1,blo[ot][1],acc[ot]);
      acc[ot]=mfma16(a1,bhi[ot][1],acc[ot]);
    }
    #pragma unroll
    for(int ot=0;ot<4;ot++)
      #pragma unroll
      for(int r=0;r<4;r++)
        rep[quad*4+r][ot*16+m]=(f16_t)acc[ot][r];
    #pragma unroll
    for(int it=0;it<2;it++){
      int rr=it*8+rr0;
      h8 vals=*(const h8*)&rep[rr][seg*8];
      *(h8*)(out+(size_t)(row0+rr)*octot+ocol0+seg*8)=vals;
    }
  }
}

// fused feature GEMM: blocks [0,5*CHV) var panels, rest ins panels
__global__ __launch_bounds__(256) void k_colres_feat(const f16_t* __restrict__ Av,const f16_t* __restrict__ Ai,
    const short* __restrict__ Bvh,const short* __restrict__ Bvl,const float* __restrict__ biasv,
    const short* __restrict__ Bih,const short* __restrict__ Bil,const float* __restrict__ biasi,
    f16_t* __restrict__ outv,f16_t* __restrict__ outi)
{
  __shared__ f16_t rep[4][16][72];
  const int wave=threadIdx.x>>6, lane=threadIdx.x&63;
  const int m=lane&15, quad=lane>>4;
  int bx=blockIdx.x;
  if(bx<5*CHV){
    int pan=bx/CHV, c=bx%CHV;
    colres_body(Av,NV_N/64,Bvh,Bvl,biasv,outv,320,pan*64,c,CHV,wave,lane,m,quad,rep[wave]);
  }else{
    bx-=5*CHV;
    int pan=bx/CHI, c=bx%CHI;
    colres_body(Ai,NI_N/64,Bih,Bil,biasi,outi,192,pan*64,c,CHI,wave,lane,m,quad,rep[wave]);
  }
}

// generic single-input column-resident GEMM (used for JK qkv)
__global__ __launch_bounds__(256) void k_colres1(const f16_t* __restrict__ A,int nrb,
    const short* __restrict__ Bh,const short* __restrict__ Bl,
    const float* __restrict__ bias,f16_t* __restrict__ out,int octot,int CH)
{
  __shared__ f16_t rep[4][16][72];
  const int wave=threadIdx.x>>6, lane=threadIdx.x&63;
  const int m=lane&15, quad=lane>>4;
  int pan=blockIdx.x/CH, c=blockIdx.x%CH;
  colres_body(A,nrb,Bh,Bl,bias,out,octot,pan*64,c,CH,wave,lane,m,quad,rep[wave]);
}

// ---------------- legacy GEMM body (float A path for osum @ Wo) ----------------
template<typename AT, typename OT>
__device__ __forceinline__ void gemm_body(const AT* __restrict__ A,int row0,
    const short* __restrict__ Bh,const short* __restrict__ Bl,
    const float* __restrict__ bias,float bias_scale,
    OT* __restrict__ out,int octot,int ocol0,int npanels,int m,int quad,int lane,
    f16_t (*rep)[72])
{
  const AT* ap=A+(size_t)(row0+m)*64+quad*8;
  constexpr bool AF16 = (sizeof(AT)==2);
  short8 ahi[2], alo[2];
  if constexpr(AF16){
    #pragma unroll
    for(int kf=0;kf<2;kf++) ahi[kf]=*(const short8*)(const void*)(ap+kf*32);
  }else{
    #pragma unroll
    for(int kf=0;kf<2;kf++){
      short8 th,tl;
      #pragma unroll
      for(int j=0;j<8;j++){ short h,l2; splitf16(ldval(&ap[kf*32+j]),h,l2); th[j]=h; tl[j]=l2; }
      ahi[kf]=th; alo[kf]=tl;
    }
  }
  for(int pan=0;pan<npanels;pan++){
    int colbase=pan*64;
    short8 bhi[4][2], blo[4][2];
    #pragma unroll
    for(int ot=0;ot<4;ot++){
      size_t o=(size_t)(colbase+ot*16+m)*64+quad*8;
      #pragma unroll
      for(int kf=0;kf<2;kf++){
        bhi[ot][kf]=*(const short8*)(Bh+o+kf*32);
        blo[ot][kf]=*(const short8*)(Bl+o+kf*32);
      }
    }
    f32x4 acc[4];
    #pragma unroll
    for(int ot=0;ot<4;ot++){
      float bv=bias[colbase+ot*16+m]*bias_scale;
      acc[ot][0]=bv; acc[ot][1]=bv; acc[ot][2]=bv; acc[ot][3]=bv;
    }
    #pragma unroll
    for(int ot=0;ot<4;ot++){
      #pragma unroll
      for(int kf=0;kf<2;kf++){
        if constexpr(!AF16) acc[ot]=mfma16(alo[kf],bhi[ot][kf],acc[ot]);
        acc[ot]=mfma16(ahi[kf],blo[ot][kf],acc[ot]);
        acc[ot]=mfma16(ahi[kf],bhi[ot][kf],acc[ot]);
      }
    }
    if constexpr(sizeof(OT)==2){
      #pragma unroll
      for(int ot=0;ot<4;ot++)
        #pragma unroll
        for(int r=0;r<4;r++)
          rep[quad*4+r][ot*16+m]=(f16_t)acc[ot][r];
      #pragma unroll
      for(int it=0;it<2;it++){
        int rr=it*8+(lane>>3), seg=lane&7;
        h8 vals=*(const h8*)&rep[rr][seg*8];
        *(h8*)(out+(size_t)(row0+rr)*octot+ocol0+colbase+seg*8)=vals;
      }
    }else{
      #pragma unroll
      for(int ot=0;ot<4;ot++){
        int col=ocol0+colbase+ot*16+m;
        #pragma unroll
        for(int r=0;r<4;r++){
          int row=row0+quad*4+r;
          stval(&out[(size_t)row*octot+col],acc[ot][r]);
        }
      }
    }
  }
}

template<typename AT, typename OT>
__global__ __launch_bounds__(256) void k_gemm64p(const AT* __restrict__ A,int N,
    const short* __restrict__ Bh,const short* __restrict__ Bl,
    const float* __restrict__ bias,float bias_scale,
    OT* __restrict__ out,int octot,int ocol0,int npanels)
{
  __shared__ f16_t rep[4][16][72];
  const int wave=threadIdx.x>>6, lane=threadIdx.x&63;
  const int m=lane&15, quad=lane>>4;
  const int row0=blockIdx.x*64+wave*16;
  if(row0>=N) return;
  gemm_body<AT,OT>(A,row0,Bh,Bl,bias,bias_scale,out,octot,ocol0,npanels,m,quad,lane,rep[wave]);
}

// ---------------- fused per-layer update (instr blocks then var blocks), x/agg f16, LDS-repacked I/O ----------------
__global__ __launch_bounds__(256) void k_update2(const f16_t* __restrict__ agg_i,const f16_t* __restrict__ agg_v,
    const short* __restrict__ wah_i,const short* __restrict__ wal_i,
    const short* __restrict__ wah_v,const short* __restrict__ wal_v,
    const float* __restrict__ ba_i,const float* __restrict__ ba_v,
    const float* __restrict__ skip_i,const float* __restrict__ skip_v,
    f16_t* __restrict__ x_i,f16_t* __restrict__ x_v,
    f16_t* __restrict__ outs,int nbi)
{
  __shared__ f16_t rep[4][16][72];
  const int wave=threadIdx.x>>6, lane=threadIdx.x&63;
  const int m=lane&15, quad=lane>>4;
  const bool isI=(int)blockIdx.x<nbi;
  const int row0=(isI?blockIdx.x:(blockIdx.x-nbi))*64+wave*16;
  const f16_t* agg=isI?agg_i:agg_v;
  const short* Wah=isI?wah_i:wah_v;
  const short* Wal=isI?wal_i:wal_v;
  const float* ba=isI?ba_i:ba_v;
  const float* skip=isI?skip_i:skip_v;
  f16_t* x=isI?x_i:x_v;
  f16_t* oo=isI?outs:nullptr;
  f16_t (*R)[72]=rep[wave];
  short8 bhi[4][2], blo[4][2];
  #pragma unroll
  for(int ot=0;ot<4;ot++){
    size_t o=(size_t)(ot*16+m)*64+quad*8;
    #pragma unroll
    for(int kf=0;kf<2;kf++){
      bhi[ot][kf]=*(const short8*)(Wah+o+kf*32);
      blo[ot][kf]=*(const short8*)(Wal+o+kf*32);
    }
  }
  const f16_t* ap=agg+(size_t)(row0+m)*64+quad*8;
  short8 ahi[2], alo[2];
  #pragma unroll
  for(int kf=0;kf<2;kf++){
    short8 th,tl;
    #pragma unroll
    for(int j=0;j<8;j++){ short h,l2; splitf16(gelu_f((float)ap[kf*32+j]),h,l2); th[j]=h; tl[j]=l2; }
    ahi[kf]=th; alo[kf]=tl;
  }
  // stage x rows into LDS (wide loads)
  int rr0=lane>>3, seg=lane&7;
  h8 x0=*(const h8*)(x+(size_t)(row0+rr0)*64+seg*8);
  h8 x1=*(const h8*)(x+(size_t)(row0+8+rr0)*64+seg*8);
  *(h8*)&R[rr0][seg*8]=x0;
  *(h8*)&R[8+rr0][seg*8]=x1;
  f32x4 acc[4];
  #pragma unroll
  for(int ot=0;ot<4;ot++){
    float bv=ba[ot*16+m];
    acc[ot][0]=bv; acc[ot][1]=bv; acc[ot][2]=bv; acc[ot][3]=bv;
  }
  #pragma unroll
  for(int ot=0;ot<4;ot++){
    #pragma unroll
    for(int kf=0;kf<2;kf++){
      acc[ot]=mfma16(alo[kf],bhi[ot][kf],acc[ot]);
      acc[ot]=mfma16(ahi[kf],blo[ot][kf],acc[ot]);
      acc[ot]=mfma16(ahi[kf],bhi[ot][kf],acc[ot]);
    }
  }
  float s=1.0f/(1.0f+__expf(-skip[0]));
  #pragma unroll
  for(int ot=0;ot<4;ot++){
    int col=ot*16+m;
    #pragma unroll
    for(int r=0;r<4;r++){
      int row=quad*4+r;
      float xn=s*acc[ot][r]+(1.0f-s)*(float)R[row][col];
      R[row][col]=(f16_t)xn;
    }
  }
  h8 o0=*(const h8*)&R[rr0][seg*8];
  h8 o1=*(const h8*)&R[8+rr0][seg*8];
  *(h8*)(x+(size_t)(row0+rr0)*64+seg*8)=o0;
  *(h8*)(x+(size_t)(row0+8+rr0)*64+seg*8)=o1;
  if(oo){
    *(h8*)(oo+(size_t)(row0+rr0)*64+seg*8)=o0;
    *(h8*)(oo+(size_t)(row0+8+rr0)*64+seg*8)=o1;
  }
}

// ---------------- edge attention: lane = (e_slot, head); in-register dots, per-node LDS combine ----------------
// esrc holds PRE-SCALED row offsets (src*stride). Layout: q|k|v contiguous blocks.
// q pre-scaled by LOG2E -> exp2 softmax. 8 edges x 8 heads per wave-iteration, zero in-loop shuffles.
__device__ __forceinline__ float edge_agg_eh(const int* __restrict__ rp,const int* __restrict__ es,
    const f16_t* __restrict__ sf,int koff,int voff,int n,int e_slot,int h,int lane,
    h2v q0,h2v q1,h2v q2,h2v q3,float* __restrict__ L)
{
  int b=__builtin_amdgcn_readfirstlane(rp[n]);
  int e=__builtin_amdgcn_readfirstlane(rp[n+1]);
  if(b==e) return 0.f;
  const float M0=-1e30f;
  float m=M0, ls=0.f;
  f2 A0={0.f,0.f},A1={0.f,0.f},A2={0.f,0.f},A3={0.f,0.f};
  const int hb=h*8;
  for(int i=b;i<e;i+=8){
    int eidx=i+e_slot;
    bool valid=eidx<e;
    int ec=valid?eidx:(e-1);
    int off=es[ec];
    const f16_t* kp=sf+(size_t)(unsigned)off+koff+hb;
    h8 kv=*(const h8*)kp;
    h8 vv=*(const h8*)(sf+(size_t)(unsigned)off+voff+hb);
    float p;
#if __has_builtin(__builtin_amdgcn_fdot2)
    p=__builtin_amdgcn_fdot2((h2v){kv[0],kv[1]},q0,0.f,false);
    p=__builtin_amdgcn_fdot2((h2v){kv[2],kv[3]},q1,p,false);
    p=__builtin_amdgcn_fdot2((h2v){kv[4],kv[5]},q2,p,false);
    p=__builtin_amdgcn_fdot2((h2v){kv[6],kv[7]},q3,p,false);
#else
    p=(float)kv[0]*(float)q0[0]+(float)kv[1]*(float)q0[1]
     +(float)kv[2]*(float)q1[0]+(float)kv[3]*(float)q1[1]
     +(float)kv[4]*(float)q2[0]+(float)kv[5]*(float)q2[1]
     +(float)kv[6]*(float)q3[0]+(float)kv[7]*(float)q3[1];
#endif
    p=valid?p:M0;
    float mn=fmaxf(m,p);
    float sc=fexp2(m-mn);
    float w=valid?fexp2(p-mn):0.f;
    ls=fmaf(ls,sc,w);
    f2 S={sc,sc}, W={w,w};
    f2 V0={(float)vv[0],(float)vv[1]}, V1={(float)vv[2],(float)vv[3]};
    f2 V2={(float)vv[4],(float)vv[5]}, V3={(float)vv[6],(float)vv[7]};
    A0=A0*S+W*V0; A1=A1*S+W*V1; A2=A2*S+W*V2; A3=A3*S+W*V3;
    m=mn;
  }
  // combine across e_slot (lanes xor 8/16/32 share the same head h)
  float mall=fmaxf(m,__shfl_xor(m,8));
  mall=fmaxf(mall,__shfl_xor(mall,16));
  mall=fmaxf(mall,__shfl_xor(mall,32));
  float scl=fexp2(m-mall);           // empty lane: exp2(-1e30-finite)=0
  ls*=scl;
  float lsall=ls+__shfl_xor(ls,8);
  lsall+=__shfl_xor(lsall,16);
  lsall+=__shfl_xor(lsall,32);
  f2 S2={scl,scl};
  A0*=S2; A1*=S2; A2*=S2; A3*=S2;
  // LDS transpose: write [e_slot][h*8+d], read [e][lane] -> result lands in feature order
  float* wp=L+e_slot*64+hb;
  f32x4 w0={A0[0],A0[1],A1[0],A1[1]};
  f32x4 w1={A2[0],A2[1],A3[0],A3[1]};
  *(f32x4*)wp=w0;
  *(f32x4*)(wp+4)=w1;
  __asm__ volatile("s_waitcnt lgkmcnt(0)" ::: "memory");
  float r=0.f;
  #pragma unroll
  for(int ee=0;ee<8;ee++) r+=L[ee*64+lane];
  float lsr=__shfl(lsall,lane>>3);   // ls for head (lane>>3) lives at lane (lane>>3)
  return r/(lsr+1e-16f);             // degree 0 -> early return; matches PyG semantics
}

// fused edge kernel: blocks [0,nbv) var destinations (vv+iv), rest instr destinations (vi)
__global__ __launch_bounds__(256) void k_edge_all(const int* __restrict__ rp_all,const int* __restrict__ es,
    const f16_t* __restrict__ var_feat,const f16_t* __restrict__ ins_feat,
    f16_t* __restrict__ agg_v,f16_t* __restrict__ agg_i,int nbv)
{
  __shared__ float lds[4][512];
  int wave=threadIdx.x>>6, lane=threadIdx.x&63;
  int e_slot=lane>>3, h=lane&7;
  float* L=lds[wave];
  if((int)blockIdx.x<nbv){
    int n=blockIdx.x*4+wave;
    const f16_t* qp=var_feat+(size_t)n*320+h*8;
    h8 qv=*(const h8*)qp;
    h2v q0={qv[0],qv[1]},q1={qv[2],qv[3]},q2={qv[4],qv[5]},q3={qv[6],qv[7]};
    float r1=edge_agg_eh(rp_all,es,var_feat,64,128,n,e_slot,h,lane,q0,q1,q2,q3,L);
    float r2=edge_agg_eh(rp_all+NV_N,es,ins_feat,64,128,n,e_slot,h,lane,q0,q1,q2,q3,L);
    agg_v[(size_t)n*64+lane]=(f16_t)(r1+r2);
  }else{
    int n=(blockIdx.x-nbv)*4+wave;
    const f16_t* qp=ins_feat+(size_t)n*192+h*8;
    h8 qv=*(const h8*)qp;
    h2v q0={qv[0],qv[1]},q1={qv[2],qv[3]},q2={qv[4],qv[5]},q3={qv[6],qv[7]};
    float r=edge_agg_eh(rp_all+2*NV_N,es,var_feat,192,256,n,e_slot,h,lane,q0,q1,q2,q3,L);
    agg_i[(size_t)n*64+lane]=(f16_t)r;
  }
}

// ---------------- jumping-knowledge 5x5 attention, one wave per node
__global__ __launch_bounds__(256) void k_jk(const f16_t* __restrict__ qkv,float* __restrict__ osum,int n_nodes){
  int wave=threadIdx.x>>6, lane=threadIdx.x&63;
  int n=blockIdx.x*4+wave;
  if(n>=n_nodes) return;
  float q[5],k[5],v[5];
  #pragma unroll
  for(int s=0;s<5;s++){
    const f16_t* p=qkv+((size_t)s*n_nodes+n)*192;
    q[s]=(float)p[lane]; k[s]=(float)p[64+lane]; v[s]=(float)p[128+lane];
  }
  float sc[5][5];
  #pragma unroll
  for(int s=0;s<5;s++)
    #pragma unroll
    for(int t=0;t<5;t++){
      float x=q[s]*k[t];
      x+=__shfl_xor(x,1); x+=__shfl_xor(x,2); x+=__shfl_xor(x,4);
      sc[s][t]=x*0.3535533905932738f;
    }
  float os=0.f;
  #pragma unroll
  for(int s=0;s<5;s++){
    float m=sc[s][0];
    #pragma unroll
    for(int t=1;t<5;t++) m=fmaxf(m,sc[s][t]);
    float den=0.f, acc=0.f;
    #pragma unroll
    for(int t=0;t<5;t++){ float e=__expf(sc[s][t]-m); den+=e; acc+=e*v[t]; }
    os+=acc/den;
  }
  osum[(size_t)n*64+lane]=os;
}

// ---------------- MLP head ----------------
struct MlpArgs{ const float *w0,*b0,*w1,*b1,*w2,*b2,*w3,*b3,*w4,*b4,*w5,*b5; };
__global__ __launch_bounds__(256) void k_mlp(const float* __restrict__ in,MlpArgs ma,float* __restrict__ out,int N){
  __shared__ float sw0[2048],sb0[32],sw1[512],sb1[16],sw2[128],sb2[8],sw3[32],sb3[4],sw4[8],sb4[2],sw5[2],sb5[1];
  for(int i=threadIdx.x;i<2048;i+=256) sw0[i]=ma.w0[i];
  for(int i=threadIdx.x;i<512;i+=256)  sw1[i]=ma.w1[i];
  if(threadIdx.x<128) sw2[threadIdx.x]=ma.w2[threadIdx.x];
  if(threadIdx.x<32){ sb0[threadIdx.x]=ma.b0[threadIdx.x]; sw3[threadIdx.x]=ma.w3[threadIdx.x]; }
  if(threadIdx.x<16) sb1[threadIdx.x]=ma.b1[threadIdx.x];
  if(threadIdx.x<8){ sb2[threadIdx.x]=ma.b2[threadIdx.x]; sw4[threadIdx.x]=ma.w4[threadIdx.x]; }
  if(threadIdx.x<4) sb3[threadIdx.x]=ma.b3[threadIdx.x];
  if(threadIdx.x<2){ sb4[threadIdx.x]=ma.b4[threadIdx.x]; sw5[threadIdx.x]=ma.w5[threadIdx.x]; }
  if(threadIdx.x==0) sb5[0]=ma.b5[0];
  __syncthreads();
  int n=blockIdx.x*256+threadIdx.x;
  if(n>=N) return;
  float a[64];
  const f32x4* p4=(const f32x4*)(in+(size_t)n*64);
  #pragma unroll
  for(int j=0;j<16;j++){ f32x4 t=p4[j]; a[4*j]=t[0]; a[4*j+1]=t[1]; a[4*j+2]=t[2]; a[4*j+3]=t[3]; }
  float h1[32];
  #pragma unroll
  for(int o=0;o<32;o++){ float s=sb0[o];
    #pragma unroll
    for(int c=0;c<64;c++) s+=a[c]*sw0[o*64+c];
    h1[o]=gelu_f(s); }
  float h2q[16];
  #pragma unroll
  for(int o=0;o<16;o++){ float s=sb1[o];
    #pragma unroll
    for(int c=0;c<32;c++) s+=h1[c]*sw1[o*32+c];
    h2q[o]=gelu_f(s); }
  float h3[8];
  #pragma unroll
  for(int o=0;o<8;o++){ float s=sb2[o];
    #pragma unroll
    for(int c=0;c<16;c++) s+=h2q[c]*sw2[o*16+c];
    h3[o]=gelu_f(s); }
  float h4[4];
  #pragma unroll
  for(int o=0;o<4;o++){ float s=sb3[o];
    #pragma unroll
    for(int c=0;c<8;c++) s+=h3[c]*sw3[o*8+c];
    h4[o]=gelu_f(s); }
  float h5[2];
  #pragma unroll
  for(int o=0;o<2;o++){ float s=sb4[o];
    #pragma unroll
    for(int c=0;c<4;c++) s+=h4[c]*sw4[o*4+c];
    h5[o]=gelu_f(s); }
  float r=sb5[0]+h5[0]*sw5[0]+h5[1]*sw5[1];
  out[n]=r;
}

// ================= host launcher =================
extern "C" void kernel_launch(void* const* d_in,const int* in_sizes,int n_in,
                              void* d_out,int out_size,void* d_ws,size_t ws_size,
                              hipStream_t stream){
  (void)in_sizes;(void)n_in;(void)out_size;(void)ws_size;
  const float* x_instr=(const float*)d_in[0];
  const float* x_var  =(const float*)d_in[1];
  const float* ba_i=(const float*)d_in[9];
  const float* skip_i=(const float*)d_in[10];
  const float* ba_v=(const float*)d_in[18];
  const float* skip_v=(const float*)d_in[19];
  const float* Wqkv=(const float*)d_in[29];
  const float* bqkv=(const float*)d_in[30];
  const float* Wo=(const float*)d_in[31];
  const float* bo=(const float*)d_in[32];
  const int* src_vv=(const int*)d_in[45];
  const int* dst_vv=(const int*)d_in[46];
  const int* src_vi=(const int*)d_in[47];
  const int* dst_vi=(const int*)d_in[48];
  const int* src_iv=(const int*)d_in[49];
  const int* dst_iv=(const int*)d_in[50];

  char* w=(char*)d_ws;
  auto alloc=[&](size_t b)->char*{ char* p=w; w+=(b+255)&~(size_t)255; return p; };
  // ---- fused CSR arrays (~12 MB) ----
  int* rp_all=(int*)alloc((size_t)(NT_N+1)*4);
  int* cnt_all=(int*)alloc((size_t)NT_N*4);
  int* cur_all=(int*)alloc((size_t)NT_N*4);
  int* bsum =(int*)alloc(640*4);
  int* boff =(int*)alloc(640*4);
  int* esrc_all=(int*)alloc((size_t)ET_N*4);
  // ---- folded + pre-split weights for all 6 layers (~2.5 MB) ----
  short* fwh_var=(short*)alloc((size_t)6*320*64*2);
  short* fwl_var=(short*)alloc((size_t)6*320*64*2);
  float* fwb_var=(float*)alloc((size_t)6*320*4);
  short* fwh_ins=(short*)alloc((size_t)6*192*64*2);
  short* fwl_ins=(short*)alloc((size_t)6*192*64*2);
  float* fwb_ins=(float*)alloc((size_t)6*192*4);
  short* wah_i=(short*)alloc((size_t)6*64*64*2);
  short* wal_i=(short*)alloc((size_t)6*64*64*2);
  short* wah_v=(short*)alloc((size_t)6*64*64*2);
  short* wal_v=(short*)alloc((size_t)6*64*64*2);
  short* qkvh=(short*)alloc(192*64*2);
  short* qkvl=(short*)alloc(192*64*2);
  short* woh=(short*)alloc(64*64*2);
  short* wol=(short*)alloc(64*64*2);
  // ---- persistent across phases: outs (f16, 21 MB) ----
  f16_t* outs=(f16_t*)alloc((size_t)5*NI_N*64*2);
  // ---- arena (140 MB), phase-overlaid ----
  char* arena=alloc((size_t)146800640);
  f16_t*  xv      =(f16_t*)(arena);                                // 16,777,216 B
  f16_t*  xi      =(f16_t*)(arena+16777216);                       //  4,194,304 B
  f16_t*  var_feat=(f16_t*)(arena+20971520);                       // 83,886,080 B (stride 320: q | k_vv | v_vv | k_vi | v_vi)
  f16_t*  ins_feat=(f16_t*)(arena+104857600);                      // 12,582,912 B (stride 192: q | k | v)
  f16_t*  agg_v   =(f16_t*)(arena+117440512);                      // 16,777,216 B
  f16_t*  agg_i   =(f16_t*)(arena+134217728);                      //  4,194,304 B
  // JK phase overlays (xv/xi/var_feat dead by then):
  f16_t*  qkv    =(f16_t*)(arena);                                 // 62,914,560 B
  float*  osum   =(float*)(arena+67108864);                        //  8,388,608 B (inside dead var_feat)
  float*  out_jk =(float*)(arena+75497472);                        //  8,388,608 B (inside dead var_feat)

  // fused CSR build
  hipMemsetAsync(cnt_all,0,(size_t)NT_N*4,stream);
  k_hist3<<<ET_N/256,256,0,stream>>>(dst_vv,dst_iv,dst_vi,cnt_all);
  int nb=NT_N/512;   // 576
  k_scan1<<<nb,512,0,stream>>>(cnt_all,NT_N,rp_all,bsum);
  k_scan2<<<1,1024,0,stream>>>(bsum,boff,nb);
  k_scan3<<<nb,512,0,stream>>>(rp_all,boff,cur_all,NT_N,nb);
  for(int wdx=0;wdx<SC_WIN;wdx++){
    int dlo=wdx*(NT_N/SC_WIN), dhi=(wdx+1)*(NT_N/SC_WIN);
    k_scatter3w<<<ET_N/256,256,0,stream>>>(src_vv,dst_vv,src_iv,dst_iv,src_vi,dst_vi,cur_all,esrc_all,dlo,dhi);
  }

  k_castx<<<(NI_N*64+NV_N*64)/256,256,0,stream>>>(x_instr,x_var,xi,xv);

  // one-time splits for JK weights
  k_split2<<<(192*64+255)/256,256,0,stream>>>(Wqkv,192*64,qkvh,qkvl);
  k_split2<<<(64*64+255)/256,256,0,stream>>>(Wo,64*64,woh,wol);

  FoldArgs fa;
  fa.Wk_i=(const float*)d_in[2]; fa.Wq_i=(const float*)d_in[3]; fa.Wv_i=(const float*)d_in[4];
  fa.bk_i=(const float*)d_in[6]; fa.bq_i=(const float*)d_in[7]; fa.bv_i=(const float*)d_in[8];
  fa.Wk_v=(const float*)d_in[11]; fa.Wq_v=(const float*)d_in[12]; fa.Wv_v=(const float*)d_in[13];
  fa.bk_v=(const float*)d_in[15]; fa.bq_v=(const float*)d_in[16]; fa.bv_v=(const float*)d_in[17];
  fa.arel_vv=(const float*)d_in[20]; fa.mrel_vv=(const float*)d_in[21]; fa.prel_vv=(const float*)d_in[22];
  fa.arel_vi=(const float*)d_in[23]; fa.mrel_vi=(const float*)d_in[24]; fa.prel_vi=(const float*)d_in[25];
  fa.arel_iv=(const float*)d_in[26]; fa.mrel_iv=(const float*)d_in[27]; fa.prel_iv=(const float*)d_in[28];
  fa.Wa_i=(const float*)d_in[5]; fa.Wa_v=(const float*)d_in[14];
  fa.fwh_var=fwh_var; fa.fwl_var=fwl_var; fa.fwh_ins=fwh_ins; fa.fwl_ins=fwl_ins;
  fa.wah_i=wah_i; fa.wal_i=wal_i; fa.wah_v=wah_v; fa.wal_v=wal_v;
  fa.fwb_var=fwb_var; fa.fwb_ins=fwb_ins;
  k_fold6<<<(6*640*64)/256,256,0,stream>>>(fa);

  for(int l=0;l<6;l++){
    k_colres_feat<<<5*CHV+3*CHI,256,0,stream>>>(xv,xi,
        fwh_var+(size_t)l*320*64,fwl_var+(size_t)l*320*64,fwb_var+l*320,
        fwh_ins+(size_t)l*192*64,fwl_ins+(size_t)l*192*64,fwb_ins+l*192,
        var_feat,ins_feat);
    k_edge_all<<<NV_N/4+NI_N/4,256,0,stream>>>(rp_all,esrc_all,var_feat,ins_feat,agg_v,agg_i,NV_N/4);
    k_update2<<<NI_N/64+NV_N/64,256,0,stream>>>(agg_i,agg_v,
        wah_i+(size_t)l*4096,wal_i+(size_t)l*4096,wah_v+(size_t)l*4096,wal_v+(size_t)l*4096,
        ba_i+l*64,ba_v+l*64,skip_i+l,skip_v+l,xi,xv,
        (l>0)?(outs+(size_t)(l-1)*NI_N*64):nullptr,NI_N/64);
  }

  // jumping knowledge + head
  k_colres1<<<3*CHQ,256,0,stream>>>(outs,5*NI_N/64,qkvh,qkvl,bqkv,qkv,192,CHQ);
  k_jk<<<NI_N/4,256,0,stream>>>(qkv,osum,NI_N);
  k_gemm64p<float,float><<<NI_N/64,256,0,stream>>>(osum,NI_N,woh,wol,bo,5.0f,out_jk,64,0,1);
  MlpArgs ma;
  ma.w0=(const float*)d_in[33]; ma.b0=(const float*)d_in[34];
  ma.w1=(const float*)d_in[35]; ma.b1=(const float*)d_in[36];
  ma.w2=(const float*)d_in[37]; ma.b2=(const float*)d_in[38];
  ma.w3=(const float*)d_in[39]; ma.b3=(const float*)d_in[40];
  ma.w4=(const float*)d_in[41]; ma.b4=(const float*)d_in[42];
  ma.w5=(const float*)d_in[43]; ma.b5=(const float*)d_in[44];
  k_mlp<<<NI_N/256,256,0,stream>>>(out_jk,ma,(float*)d_out,NI_N);
}